// Round 4
// baseline (15286.626 us; speedup 1.0000x reference)
//
#include <hip/hip_runtime.h>
#include <stdint.h>

#define BATCH 32
#define SEQ   128       // S == T == 128
#define HID   512
#define VTOK  32000

typedef unsigned short u16;
typedef unsigned int   u32;
typedef float    f32x4  __attribute__((ext_vector_type(4)));
typedef short    short8 __attribute__((ext_vector_type(8)));
typedef _Float16 half2t __attribute__((ext_vector_type(2)));

__device__ __forceinline__ u16 f2bf(float f) {
    u32 u = __builtin_bit_cast(u32, f);
    return (u16)((u + 0x7FFFu + ((u >> 16) & 1u)) >> 16);
}
__device__ __forceinline__ float bf2f(u16 v) {
    u32 u = ((u32)v) << 16; return __builtin_bit_cast(float, u);
}
__device__ __forceinline__ float dot2f16(u32 a, u32 b, float c) {
#if __has_builtin(__builtin_amdgcn_fdot2)
    return __builtin_amdgcn_fdot2(__builtin_bit_cast(half2t, a),
                                  __builtin_bit_cast(half2t, b), c, false);
#else
    half2t av = __builtin_bit_cast(half2t, a), bv = __builtin_bit_cast(half2t, b);
    return c + (float)av.x * (float)bv.x + (float)av.y * (float)bv.y;
#endif
}
__device__ __forceinline__ void dot4x(float& acc, uint4 wv, uint4 hv) {
    acc = dot2f16(wv.x, hv.x, acc); acc = dot2f16(wv.y, hv.y, acc);
    acc = dot2f16(wv.z, hv.z, acc); acc = dot2f16(wv.w, hv.w, acc);
}
// 512-long f16 dot product (both operands contiguous, 16B aligned)
__device__ __forceinline__ float dot512(const _Float16* __restrict__ w,
                                        const _Float16* __restrict__ h) {
    const uint4* wv = (const uint4*)w;
    const uint4* hv = (const uint4*)h;
    float acc = 0.f;
    #pragma unroll 8
    for (int k = 0; k < 64; ++k) dot4x(acc, wv[k], hv[k]);
    return acc;
}

__device__ __forceinline__ float fexp2(float x) { return __builtin_amdgcn_exp2f(x); }
__device__ __forceinline__ float frcp(float x)  { return __builtin_amdgcn_rcpf(x); }
__device__ __forceinline__ float sigmoid_f(float x) {
    return frcp(1.f + fexp2(-1.442695040888963f * x));
}
__device__ __forceinline__ float tanh_f(float x) {
    return 1.f - 2.f * frcp(1.f + fexp2(2.885390081777927f * x));
}

// ---------------- prep kernels ----------------

// f32 [K,N] -> bf16 [N,K]
__global__ __launch_bounds__(256) void transpose_cvt(
    const float* __restrict__ src, u16* __restrict__ dst, int K, int N)
{
    __shared__ float tile[32][33];
    const int n0 = blockIdx.x * 32, k0 = blockIdx.y * 32;
    const int tx = threadIdx.x & 31, ty = threadIdx.x >> 5;
    #pragma unroll
    for (int j = 0; j < 32; j += 8)
        tile[ty + j][tx] = src[(size_t)(k0 + ty + j) * N + n0 + tx];
    __syncthreads();
    #pragma unroll
    for (int j = 0; j < 32; j += 8)
        dst[(size_t)(n0 + ty + j) * K + k0 + tx] = f2bf(tile[tx][ty + j]);
}

// f32 [K,N] -> f16 [N,K] (column-major weights for GEMV phases)
__global__ __launch_bounds__(256) void transpose_cvt_f16(
    const float* __restrict__ src, _Float16* __restrict__ dst, int K, int N)
{
    __shared__ float tile[32][33];
    const int n0 = blockIdx.x * 32, k0 = blockIdx.y * 32;
    const int tx = threadIdx.x & 31, ty = threadIdx.x >> 5;
    #pragma unroll
    for (int j = 0; j < 32; j += 8)
        tile[ty + j][tx] = src[(size_t)(k0 + ty + j) * N + n0 + tx];
    __syncthreads();
    #pragma unroll
    for (int j = 0; j < 32; j += 8)
        dst[(size_t)(n0 + ty + j) * K + k0 + tx] = (_Float16)tile[tx][ty + j];
}

// f32 -> bf16 (flat), 8 elems/thread
__global__ __launch_bounds__(256) void cvt_f32_bf16(
    const float* __restrict__ src, u16* __restrict__ dst)
{
    const size_t i = ((size_t)blockIdx.x * 256 + threadIdx.x) * 8;
    float4 v0 = *(const float4*)(src + i);
    float4 v1 = *(const float4*)(src + i + 4);
    uint4 pk;
    pk.x = (u32)f2bf(v0.x) | ((u32)f2bf(v0.y) << 16);
    pk.y = (u32)f2bf(v0.z) | ((u32)f2bf(v0.w) << 16);
    pk.z = (u32)f2bf(v1.x) | ((u32)f2bf(v1.y) << 16);
    pk.w = (u32)f2bf(v1.z) | ((u32)f2bf(v1.w) << 16);
    *(uint4*)(dst + i) = pk;
}

// embedding gather -> bf16 rows [4096, 512]
__global__ __launch_bounds__(128) void gather_emb_bf16(
    const int* __restrict__ idx, const float* __restrict__ emb, u16* __restrict__ out)
{
    const int r = blockIdx.x;
    const int token = idx[r];
    const int i = threadIdx.x * 4;
    float4 v = *(const float4*)(emb + (size_t)token * 512 + i);
    uint2 pk;
    pk.x = (u32)f2bf(v.x) | ((u32)f2bf(v.y) << 16);
    pk.y = (u32)f2bf(v.z) | ((u32)f2bf(v.w) << 16);
    *(uint2*)(out + (size_t)r * 512 + i) = pk;
}

__global__ __launch_bounds__(512) void init_state(float* hf32, _Float16* hf16)
{
    const int i = blockIdx.x * 512 + threadIdx.x;
    hf32[i] = 0.f; hf16[i] = (_Float16)0.f;
}

// ---------------- MFMA GEMM:  C[M,N](f32) = A[M,K](bf16) * BT[N,K](bf16) + bias ----------------
__global__ __launch_bounds__(256) void gemm_bf16(
    const u16* __restrict__ A, const u16* __restrict__ BT,
    const float* __restrict__ bias, float* __restrict__ C,
    int M, int N, int K)
{
    __shared__ __align__(16) u16 As[128][40];
    __shared__ __align__(16) u16 Bs[128][40];
    const int tid  = threadIdx.x;
    const int lane = tid & 63, wave = tid >> 6;
    const int wm = (wave & 1) * 64, wn = (wave >> 1) * 64;
    const int lrow = lane & 15, lk = (lane >> 4) * 8;
    const int srow = tid >> 2, skof = (tid & 3) * 8;
    const size_t K_ = (size_t)K;
    const u16* Ag = A + ((size_t)blockIdx.y * 128 + srow) * K_ + skof;
    const u16* Bg = BT + ((size_t)blockIdx.x * 128 + srow) * K_ + skof;
    f32x4 acc[4][4] = {};
    for (int k0 = 0; k0 < K; k0 += 32) {
        uint4 a0 = *(const uint4*)(Ag + k0);
        uint4 a1 = *(const uint4*)(Ag + 64 * K_ + k0);
        uint4 b0 = *(const uint4*)(Bg + k0);
        uint4 b1 = *(const uint4*)(Bg + 64 * K_ + k0);
        __syncthreads();
        *(uint4*)&As[srow][skof]      = a0;
        *(uint4*)&As[srow + 64][skof] = a1;
        *(uint4*)&Bs[srow][skof]      = b0;
        *(uint4*)&Bs[srow + 64][skof] = b1;
        __syncthreads();
        short8 af[4], bf[4];
        #pragma unroll
        for (int i = 0; i < 4; ++i) af[i] = *(const short8*)&As[wm + i * 16 + lrow][lk];
        #pragma unroll
        for (int j = 0; j < 4; ++j) bf[j] = *(const short8*)&Bs[wn + j * 16 + lrow][lk];
        #pragma unroll
        for (int i = 0; i < 4; ++i)
            #pragma unroll
            for (int j = 0; j < 4; ++j)
                acc[i][j] = __builtin_amdgcn_mfma_f32_16x16x32_bf16(af[i], bf[j], acc[i][j], 0, 0, 0);
    }
    const int crow0 = blockIdx.y * 128 + wm + (lane >> 4) * 4;
    const int ccol0 = blockIdx.x * 128 + wn + (lane & 15);
    #pragma unroll
    for (int j = 0; j < 4; ++j) {
        const float bv = bias ? bias[ccol0 + j * 16] : 0.f;
        #pragma unroll
        for (int i = 0; i < 4; ++i)
            #pragma unroll
            for (int rr = 0; rr < 4; ++rr)
                C[(size_t)(crow0 + i * 16 + rr) * N + (ccol0 + j * 16)] = acc[i][j][rr] + bv;
    }
}

// ============ per-timestep phase kernels: thread = (b = tid&31, col = wg*16 + tid>>5) ============

// encoder phase 1: a = h@Urz col; fuse gates. c in [0,1024)
__global__ __launch_bounds__(512) void enc_e1(
    const float* __restrict__ gx, int t,
    const _Float16* __restrict__ hf16, const _Float16* __restrict__ UrzT,
    const float* __restrict__ brz,
    _Float16* __restrict__ rh, float* __restrict__ zb)
{
    const int tid = threadIdx.x, b = tid & 31, cl = tid >> 5;
    const int c = blockIdx.x * 16 + cl;
    const float a = dot512(UrzT + (size_t)c * 512, hf16 + b * 512);
    const float gxr = gx[((size_t)(b * SEQ + t)) * 1536 + c];
    if (c < 512) {
        const float r = sigmoid_f(gxr + a + brz[c]);
        rh[b * 512 + c] = (_Float16)(r * (float)hf16[b * 512 + c]);
    } else {
        zb[(c - 512) * 32 + b] = sigmoid_f(gxr + a + brz[c]);
    }
}

// encoder phase 2: un = rh@Un col; h update + stores. c in [0,512)
__global__ __launch_bounds__(512) void enc_e2(
    const float* __restrict__ gx, int t,
    float* __restrict__ hf32, _Float16* __restrict__ hf16,
    const _Float16* __restrict__ UnT, const _Float16* __restrict__ rh,
    const float* __restrict__ zb, const float* __restrict__ bn,
    u16* __restrict__ enc_hs, _Float16* __restrict__ spack)
{
    const int tid = threadIdx.x, b = tid & 31, cl = tid >> 5;
    const int c = blockIdx.x * 16 + cl;
    const float un = dot512(UnT + (size_t)c * 512, rh + b * 512);
    const float n = tanh_f(gx[((size_t)(b * SEQ + t)) * 1536 + 1024 + c] + un + bn[c]);
    const float z = zb[c * 32 + b];
    const float hold = hf32[b * 512 + c];
    const float hn = (1.f - z) * hold + z * n;
    hf32[b * 512 + c] = hn;
    hf16[b * 512 + c] = (_Float16)hn;
    enc_hs[(size_t)(b * SEQ + t) * 512 + c] = f2bf(hn);
    spack[(((size_t)b * 16 + (t >> 3)) * 512 + c) * 8 + (t & 7)] = (_Float16)hn;
}

// decoder K1: hrz + hWs GEMV. c in [0,1536): 0-1023 Urz -> aP[c][b], 1024+ Ws -> aWs[b][c-1024]
__global__ __launch_bounds__(512) void dec_k1(
    const _Float16* __restrict__ hf16, const _Float16* __restrict__ UrzT,
    const _Float16* __restrict__ WsT,
    float* __restrict__ aP, float* __restrict__ aWs)
{
    const int tid = threadIdx.x, b = tid & 31, cl = tid >> 5;
    const int c = blockIdx.x * 16 + cl;
    const _Float16* w = (c < 1024) ? (UrzT + (size_t)c * 512)
                                   : (WsT + (size_t)(c - 1024) * 512);
    const float a = dot512(w, hf16 + b * 512);
    if (c < 1024) aP[c * 32 + b] = a;
    else          aWs[b * 512 + (c - 1024)] = a;
}

// decoder K2: attention per batch element (WG = b)
__global__ __launch_bounds__(512) void dec_k2(
    const u16* __restrict__ wh_bf, const _Float16* __restrict__ spack,
    const float* __restrict__ attn_v, const float* __restrict__ aWs,
    _Float16* __restrict__ ctxf, u16* __restrict__ hctx, int t)
{
    const int b = blockIdx.x, tid = threadIdx.x;
    __shared__ float hWsL[528], avL[528];   // 4 groups of 128, stride 132 (bank-spread)
    __shared__ u32 attnp[64];
    __shared__ float redE[512];
    {
        const int g = tid >> 7, i = tid & 127;
        hWsL[g * 132 + i] = aWs[b * 512 + tid];
        avL[g * 132 + i]  = attn_v[tid];
    }
    __syncthreads();
    // energy partials: thread -> (s = tid>>2, quarter q = tid&3, 128 dims each)
    {
        const int s = tid >> 2, q = tid & 3;
        const u16* whr = wh_bf + ((size_t)(b * SEQ + s)) * 512 + q * 128;
        const float* hwp = &hWsL[q * 132];
        const float* vvp = &avL[q * 132];
        float e = 0.f;
        #pragma unroll 4
        for (int i = 0; i < 128; i += 8) {
            uint4 wv = *(const uint4*)(whr + i);
            float4 h0v = *(const float4*)(hwp + i);
            float4 h1v = *(const float4*)(hwp + i + 4);
            float4 v0 = *(const float4*)(vvp + i);
            float4 v1 = *(const float4*)(vvp + i + 4);
            e += v0.x * tanh_f(bf2f((u16)(wv.x & 0xFFFF)) + h0v.x)
               + v0.y * tanh_f(bf2f((u16)(wv.x >> 16))    + h0v.y)
               + v0.z * tanh_f(bf2f((u16)(wv.y & 0xFFFF)) + h0v.z)
               + v0.w * tanh_f(bf2f((u16)(wv.y >> 16))    + h0v.w)
               + v1.x * tanh_f(bf2f((u16)(wv.z & 0xFFFF)) + h1v.x)
               + v1.y * tanh_f(bf2f((u16)(wv.z >> 16))    + h1v.y)
               + v1.z * tanh_f(bf2f((u16)(wv.w & 0xFFFF)) + h1v.z)
               + v1.w * tanh_f(bf2f((u16)(wv.w >> 16))    + h1v.w);
        }
        redE[tid] = e;
    }
    __syncthreads();
    if (tid < 64) {
        float e0 = redE[4 * tid] + redE[4 * tid + 1] + redE[4 * tid + 2] + redE[4 * tid + 3];
        float e1 = redE[4 * (tid + 64)] + redE[4 * (tid + 64) + 1]
                 + redE[4 * (tid + 64) + 2] + redE[4 * (tid + 64) + 3];
        float m = fmaxf(e0, e1);
        for (int o = 32; o >= 1; o >>= 1) m = fmaxf(m, __shfl_xor(m, o));
        float p0 = fexp2((e0 - m) * 1.442695040888963f);
        float p1 = fexp2((e1 - m) * 1.442695040888963f);
        float ss = p0 + p1;
        for (int o = 32; o >= 1; o >>= 1) ss += __shfl_xor(ss, o);
        const float inv = frcp(ss);
        ((u16*)attnp)[tid]      = __builtin_bit_cast(u16, (_Float16)(p0 * inv));
        ((u16*)attnp)[tid + 64] = __builtin_bit_cast(u16, (_Float16)(p1 * inv));
    }
    __syncthreads();
    // ctx[i] = sum_s attn[s] * enc_hs[b,s,i]
    {
        float cv = 0.f;
        const _Float16* sp = spack + (((size_t)b * 16) * 512 + tid) * 8;
        #pragma unroll 4
        for (int sb = 0; sb < 16; ++sb) {
            uint4 sv = *(const uint4*)(sp + (size_t)sb * 512 * 8);
            uint4 ap = *(const uint4*)&attnp[sb * 4];
            dot4x(cv, sv, ap);
        }
        ctxf[b * 512 + tid] = (_Float16)cv;
        hctx[((size_t)(b * SEQ + t)) * 1024 + 512 + tid] = f2bf(cv);
    }
}

// decoder K3: gxc = ctx@WxC col + fuse gates/rh. c in [0,1536)
__global__ __launch_bounds__(512) void dec_k3(
    const float* __restrict__ gxe, int t,
    const _Float16* __restrict__ hf16, const _Float16* __restrict__ ctxf,
    const _Float16* __restrict__ WxCT, const float* __restrict__ aP,
    const float* __restrict__ brz,
    _Float16* __restrict__ rh, float* __restrict__ zb, float* __restrict__ gn)
{
    const int tid = threadIdx.x, b = tid & 31, cl = tid >> 5;
    const int c = blockIdx.x * 16 + cl;
    const float a = dot512(WxCT + (size_t)c * 512, ctxf + b * 512);
    const float gxr = gxe[((size_t)(b * SEQ + t)) * 1536 + c];
    if (c < 512) {
        const float r = sigmoid_f(gxr + a + aP[c * 32 + b] + brz[c]);
        rh[b * 512 + c] = (_Float16)(r * (float)hf16[b * 512 + c]);
    } else if (c < 1024) {
        zb[(c - 512) * 32 + b] = sigmoid_f(gxr + a + aP[c * 32 + b] + brz[c]);
    } else {
        gn[(c - 1024) * 32 + b] = gxr + a;
    }
}

// decoder K4: un = rh@Un col; h update + hctx store. c in [0,512)
__global__ __launch_bounds__(512) void dec_k4(
    float* __restrict__ hf32, _Float16* __restrict__ hf16,
    const _Float16* __restrict__ UnT, const _Float16* __restrict__ rh,
    const float* __restrict__ zb, const float* __restrict__ gn,
    const float* __restrict__ bn, u16* __restrict__ hctx, int t)
{
    const int tid = threadIdx.x, b = tid & 31, cl = tid >> 5;
    const int c = blockIdx.x * 16 + cl;
    const float un = dot512(UnT + (size_t)c * 512, rh + b * 512);
    const float n = tanh_f(gn[c * 32 + b] + un + bn[c]);
    const float z = zb[c * 32 + b];
    const float hold = hf32[b * 512 + c];
    const float hn = (1.f - z) * hold + z * n;
    hf32[b * 512 + c] = hn;
    hf16[b * 512 + c] = (_Float16)hn;
    hctx[((size_t)(b * SEQ + t)) * 1024 + c] = f2bf(hn);
}

// ---------------- log_softmax per row, in-place on [4096, 32000] ----------------
__global__ __launch_bounds__(256) void log_softmax_rows(float* __restrict__ out)
{
    const int row = blockIdx.x, tid = threadIdx.x;
    float* p = out + (size_t)row * VTOK;
    __shared__ float rb[4];
    float m = -3.0e38f;
    for (int i = tid * 4; i < VTOK; i += 1024) {
        float4 v = *(const float4*)(p + i);
        m = fmaxf(m, fmaxf(fmaxf(v.x, v.y), fmaxf(v.z, v.w)));
    }
    for (int o = 32; o >= 1; o >>= 1) m = fmaxf(m, __shfl_xor(m, o));
    if ((tid & 63) == 0) rb[tid >> 6] = m;
    __syncthreads();
    m = fmaxf(fmaxf(rb[0], rb[1]), fmaxf(rb[2], rb[3]));
    float s = 0.f;
    for (int i = tid * 4; i < VTOK; i += 1024) {
        float4 v = *(const float4*)(p + i);
        s += fexp2((v.x - m) * 1.442695040888963f) + fexp2((v.y - m) * 1.442695040888963f)
           + fexp2((v.z - m) * 1.442695040888963f) + fexp2((v.w - m) * 1.442695040888963f);
    }
    for (int o = 32; o >= 1; o >>= 1) s += __shfl_xor(s, o);
    __syncthreads();
    if ((tid & 63) == 0) rb[tid >> 6] = s;
    __syncthreads();
    s = rb[0] + rb[1] + rb[2] + rb[3];
    const float lse = m + __builtin_amdgcn_logf(s) * 0.6931471805599453f;
    for (int i = tid * 4; i < VTOK; i += 1024) {
        float4 v = *(const float4*)(p + i);
        v.x -= lse; v.y -= lse; v.z -= lse; v.w -= lse;
        *(float4*)(p + i) = v;
    }
}

// ---------------- host launcher ----------------
extern "C" void kernel_launch(void* const* d_in, const int* in_sizes, int n_in,
                              void* d_out, int out_size, void* d_ws, size_t ws_size,
                              hipStream_t stream)
{
    (void)in_sizes; (void)n_in; (void)out_size; (void)ws_size;
    const int*   src       = (const int*)  d_in[0];
    const int*   tgt       = (const int*)  d_in[1];
    const float* enc_embed = (const float*)d_in[2];
    const float* enc_Wx    = (const float*)d_in[3];
    const float* enc_bx    = (const float*)d_in[4];
    const float* enc_Urz   = (const float*)d_in[5];
    const float* enc_brz   = (const float*)d_in[6];
    const float* enc_Un    = (const float*)d_in[7];
    const float* enc_bn    = (const float*)d_in[8];
    const float* dec_embed = (const float*)d_in[9];
    const float* dec_Wx    = (const float*)d_in[10];
    const float* dec_bx    = (const float*)d_in[11];
    const float* dec_Urz   = (const float*)d_in[12];
    const float* dec_brz   = (const float*)d_in[13];
    const float* dec_Un    = (const float*)d_in[14];
    const float* dec_bn    = (const float*)d_in[15];
    const float* attn_Wh   = (const float*)d_in[16];
    const float* attn_Ws   = (const float*)d_in[17];
    const float* attn_v    = (const float*)d_in[18];
    const float* out_W     = (const float*)d_in[19];
    const float* out_b     = (const float*)d_in[20];

    // --- scratch carved out of d_out (524,288,000 B); all dead before the final GEMM overwrites ---
    char* ob = (char*)d_out;
    float*    gx_enc  = (float*)   (ob + 0);          // 25165824
    float*    gxe_dec = (float*)   (ob + 25165824);   // 25165824
    float*    wh_enc  = (float*)   (ob + 50331648);   // 8388608
    u16*      Aenc    = (u16*)     (ob + 58720256);   // 4194304
    u16*      Adec    = (u16*)     (ob + 62914560);   // 4194304
    u16*      enc_hs  = (u16*)     (ob + 67108864);   // 4194304
    _Float16* spack   = (_Float16*)(ob + 71303168);   // 4194304
    u16*      wh_bf   = (u16*)     (ob + 75497472);   // 4194304
    u16*      encWxT  = (u16*)     (ob + 79691776);   // 1572864
    u16*      decWxET = (u16*)     (ob + 81264640);   // 1572864
    u16*      WhT     = (u16*)     (ob + 82837504);   // 524288
    _Float16* UrzET   = (_Float16*)(ob + 83361792);   // 1048576
    _Float16* UnET    = (_Float16*)(ob + 84410368);   // 524288
    _Float16* UrzDT   = (_Float16*)(ob + 84934656);   // 1048576
    _Float16* UnDT    = (_Float16*)(ob + 85983232);   // 524288
    _Float16* WsT     = (_Float16*)(ob + 86507520);   // 524288
    _Float16* WxCT    = (_Float16*)(ob + 87031808);   // 1572864
    float*    hf32    = (float*)   (ob + 88604672);   // 65536
    _Float16* hf16    = (_Float16*)(ob + 88670208);   // 32768
    _Float16* rh_f16  = (_Float16*)(ob + 88702976);   // 32768
    float*    zbuf    = (float*)   (ob + 88735744);   // 65536  [512][32]
    float*    gnD     = (float*)   (ob + 88801280);   // 65536  [512][32]
    float*    aP      = (float*)   (ob + 88866816);   // 196608 [1536][32]
    float*    aWs     = (float*)   (ob + 89063424);   // 65536  [32][512]
    _Float16* ctxf    = (_Float16*)(ob + 89128960);   // 32768

    // --- d_ws: only what must coexist with the final GEMM's output ---
    char* wb = (char*)d_ws;
    u16* outWT = (u16*)(wb + 0);          // 65536000
    u16* hctx  = (u16*)(wb + 65536000);   // 8388608

    // prep: bf16 transposes (MFMA GEMM B^T) + f16 col-major weights (GEMV phases)
    transpose_cvt<<<dim3(48, 16),   256, 0, stream>>>(enc_Wx,  encWxT, 512, 1536);
    transpose_cvt<<<dim3(48, 16),   256, 0, stream>>>(dec_Wx,  decWxET,512, 1536);
    transpose_cvt<<<dim3(16, 16),   256, 0, stream>>>(attn_Wh, WhT,    512, 512);
    transpose_cvt<<<dim3(1000, 32), 256, 0, stream>>>(out_W,   outWT, 1024, 32000);
    transpose_cvt_f16<<<dim3(32, 16), 256, 0, stream>>>(enc_Urz, UrzET, 512, 1024);
    transpose_cvt_f16<<<dim3(16, 16), 256, 0, stream>>>(enc_Un,  UnET,  512, 512);
    transpose_cvt_f16<<<dim3(32, 16), 256, 0, stream>>>(dec_Urz, UrzDT, 512, 1024);
    transpose_cvt_f16<<<dim3(16, 16), 256, 0, stream>>>(dec_Un,  UnDT,  512, 512);
    transpose_cvt_f16<<<dim3(16, 16), 256, 0, stream>>>(attn_Ws, WsT,   512, 512);
    transpose_cvt_f16<<<dim3(48, 16), 256, 0, stream>>>(dec_Wx + (size_t)512 * 1536, WxCT, 512, 1536);
    gather_emb_bf16<<<4096, 128, 0, stream>>>(src, enc_embed, Aenc);
    gather_emb_bf16<<<4096, 128, 0, stream>>>(tgt, dec_embed, Adec);

    // batched input-projection GEMMs
    gemm_bf16<<<dim3(12, 32), 256, 0, stream>>>(Aenc, encWxT,  enc_bx, gx_enc,  4096, 1536, 512);
    gemm_bf16<<<dim3(12, 32), 256, 0, stream>>>(Adec, decWxET, dec_bx, gxe_dec, 4096, 1536, 512);

    init_state<<<32, 512, 0, stream>>>(hf32, hf16);

    // encoder: 2 wide kernels per timestep
    for (int t = 0; t < SEQ; ++t) {
        enc_e1<<<64, 512, 0, stream>>>(gx_enc, t, hf16, UrzET, enc_brz, rh_f16, zbuf);
        enc_e2<<<32, 512, 0, stream>>>(gx_enc, t, hf32, hf16, UnET, rh_f16, zbuf, enc_bn,
                                       enc_hs, spack);
    }

    // wh_enc = enc_hs @ attn_Wh; -> bf16
    gemm_bf16<<<dim3(4, 32), 256, 0, stream>>>(enc_hs, WhT, nullptr, wh_enc, 4096, 512, 512);
    cvt_f32_bf16<<<1024, 256, 0, stream>>>(wh_enc, wh_bf);

    // decoder: 4 wide kernels per timestep (h carried over from encoder final state)
    for (int t = 0; t < SEQ; ++t) {
        dec_k1<<<96, 512, 0, stream>>>(hf16, UrzDT, WsT, aP, aWs);
        dec_k2<<<32, 512, 0, stream>>>(wh_bf, spack, attn_v, aWs, ctxf, hctx, t);
        dec_k3<<<96, 512, 0, stream>>>(gxe_dec, t, hf16, ctxf, WxCT, aP, dec_brz,
                                       rh_f16, zbuf, gnD);
        dec_k4<<<32, 512, 0, stream>>>(hf32, hf16, UnDT, rh_f16, zbuf, gnD, dec_bn, hctx, t);
    }

    // output projection (overwrites ALL of d_out) + in-place log_softmax
    gemm_bf16<<<dim3(250, 32), 256, 0, stream>>>(hctx, outWT, out_b, (float*)d_out, 4096, VTOK, 1024);
    log_softmax_rows<<<4096, 256, 0, stream>>>((float*)d_out);
}

// Round 5
// 11043.691 us; speedup vs baseline: 1.3842x; 1.3842x over previous
//
#include <hip/hip_runtime.h>
#include <stdint.h>

#define BATCH 32
#define SEQ   128       // S == T == 128
#define HID   512
#define VTOK  32000
#define NWG   64

typedef unsigned short u16;
typedef unsigned int   u32;
typedef float    f32x4  __attribute__((ext_vector_type(4)));
typedef short    short8 __attribute__((ext_vector_type(8)));
typedef _Float16 half2t __attribute__((ext_vector_type(2)));

__device__ __forceinline__ u16 f2bf(float f) {
    u32 u = __builtin_bit_cast(u32, f);
    return (u16)((u + 0x7FFFu + ((u >> 16) & 1u)) >> 16);
}
__device__ __forceinline__ float bf2f(u16 v) {
    u32 u = ((u32)v) << 16; return __builtin_bit_cast(float, u);
}
__device__ __forceinline__ float dot2f16(u32 a, u32 b, float c) {
#if __has_builtin(__builtin_amdgcn_fdot2)
    return __builtin_amdgcn_fdot2(__builtin_bit_cast(half2t, a),
                                  __builtin_bit_cast(half2t, b), c, false);
#else
    half2t av = __builtin_bit_cast(half2t, a), bv = __builtin_bit_cast(half2t, b);
    return c + (float)av.x * (float)bv.x + (float)av.y * (float)bv.y;
#endif
}
__device__ __forceinline__ void dot4x(float& acc, uint4 wv, uint4 hv) {
    acc = dot2f16(wv.x, hv.x, acc); acc = dot2f16(wv.y, hv.y, acc);
    acc = dot2f16(wv.z, hv.z, acc); acc = dot2f16(wv.w, hv.w, acc);
}
// 512-long f16 dot: w in LDS row, h in global
__device__ __forceinline__ float dot512_lg(const _Float16* __restrict__ wl,
                                           const _Float16* __restrict__ hg) {
    float acc = 0.f;
    #pragma unroll 8
    for (int k = 0; k < 64; ++k) {
        uint4 wv = *(const uint4*)(wl + k * 8);
        uint4 hv = *(const uint4*)(hg + k * 8);
        dot4x(acc, wv, hv);
    }
    return acc;
}

__device__ __forceinline__ float fexp2(float x) { return __builtin_amdgcn_exp2f(x); }
__device__ __forceinline__ float frcp(float x)  { return __builtin_amdgcn_rcpf(x); }
__device__ __forceinline__ float sigmoid_f(float x) {
    return frcp(1.f + fexp2(-1.442695040888963f * x));
}
__device__ __forceinline__ float tanh_f(float x) {
    return 1.f - 2.f * frcp(1.f + fexp2(2.885390081777927f * x));
}

// sense-reversing grid barrier: bar[0]=cnt, bar[16]=gen (device-scope)
__device__ __forceinline__ void gbar(u32* bar) {
    __syncthreads();
    if (threadIdx.x == 0) {
        __threadfence();
        u32 g = __hip_atomic_load(bar + 16, __ATOMIC_RELAXED, __HIP_MEMORY_SCOPE_AGENT);
        u32 a = __hip_atomic_fetch_add(bar, 1u, __ATOMIC_ACQ_REL, __HIP_MEMORY_SCOPE_AGENT);
        if (a == (u32)(NWG - 1)) {
            __hip_atomic_store(bar, 0u, __ATOMIC_RELAXED, __HIP_MEMORY_SCOPE_AGENT);
            __hip_atomic_store(bar + 16, g + 1u, __ATOMIC_RELEASE, __HIP_MEMORY_SCOPE_AGENT);
        } else {
            while (__hip_atomic_load(bar + 16, __ATOMIC_ACQUIRE, __HIP_MEMORY_SCOPE_AGENT) == g)
                __builtin_amdgcn_s_sleep(2);
        }
        __threadfence();
    }
    __syncthreads();
}

// ---------------- prep kernels ----------------

__global__ __launch_bounds__(256) void transpose_cvt(
    const float* __restrict__ src, u16* __restrict__ dst, int K, int N)
{
    __shared__ float tile[32][33];
    const int n0 = blockIdx.x * 32, k0 = blockIdx.y * 32;
    const int tx = threadIdx.x & 31, ty = threadIdx.x >> 5;
    #pragma unroll
    for (int j = 0; j < 32; j += 8)
        tile[ty + j][tx] = src[(size_t)(k0 + ty + j) * N + n0 + tx];
    __syncthreads();
    #pragma unroll
    for (int j = 0; j < 32; j += 8)
        dst[(size_t)(n0 + ty + j) * K + k0 + tx] = f2bf(tile[tx][ty + j]);
}

__global__ __launch_bounds__(256) void transpose_cvt_f16(
    const float* __restrict__ src, _Float16* __restrict__ dst, int K, int N)
{
    __shared__ float tile[32][33];
    const int n0 = blockIdx.x * 32, k0 = blockIdx.y * 32;
    const int tx = threadIdx.x & 31, ty = threadIdx.x >> 5;
    #pragma unroll
    for (int j = 0; j < 32; j += 8)
        tile[ty + j][tx] = src[(size_t)(k0 + ty + j) * N + n0 + tx];
    __syncthreads();
    #pragma unroll
    for (int j = 0; j < 32; j += 8)
        dst[(size_t)(n0 + ty + j) * K + k0 + tx] = (_Float16)tile[tx][ty + j];
}

__global__ __launch_bounds__(256) void cvt_f32_bf16(
    const float* __restrict__ src, u16* __restrict__ dst)
{
    const size_t i = ((size_t)blockIdx.x * 256 + threadIdx.x) * 8;
    float4 v0 = *(const float4*)(src + i);
    float4 v1 = *(const float4*)(src + i + 4);
    uint4 pk;
    pk.x = (u32)f2bf(v0.x) | ((u32)f2bf(v0.y) << 16);
    pk.y = (u32)f2bf(v0.z) | ((u32)f2bf(v0.w) << 16);
    pk.z = (u32)f2bf(v1.x) | ((u32)f2bf(v1.y) << 16);
    pk.w = (u32)f2bf(v1.z) | ((u32)f2bf(v1.w) << 16);
    *(uint4*)(dst + i) = pk;
}

__global__ __launch_bounds__(128) void gather_emb_bf16(
    const int* __restrict__ idx, const float* __restrict__ emb, u16* __restrict__ out)
{
    const int r = blockIdx.x;
    const int token = idx[r];
    const int i = threadIdx.x * 4;
    float4 v = *(const float4*)(emb + (size_t)token * 512 + i);
    uint2 pk;
    pk.x = (u32)f2bf(v.x) | ((u32)f2bf(v.y) << 16);
    pk.y = (u32)f2bf(v.z) | ((u32)f2bf(v.w) << 16);
    *(uint2*)(out + (size_t)r * 512 + i) = pk;
}

__global__ __launch_bounds__(512) void init_state(float* hf32, _Float16* hf16, u32* bar)
{
    const int i = blockIdx.x * 512 + threadIdx.x;
    hf32[i] = 0.f; hf16[i] = (_Float16)0.f;
    if (blockIdx.x == 0 && threadIdx.x < 64) bar[threadIdx.x] = 0u;
}

// ---------------- MFMA GEMM ----------------
__global__ __launch_bounds__(256) void gemm_bf16(
    const u16* __restrict__ A, const u16* __restrict__ BT,
    const float* __restrict__ bias, float* __restrict__ C,
    int M, int N, int K)
{
    __shared__ __align__(16) u16 As[128][40];
    __shared__ __align__(16) u16 Bs[128][40];
    const int tid  = threadIdx.x;
    const int lane = tid & 63, wave = tid >> 6;
    const int wm = (wave & 1) * 64, wn = (wave >> 1) * 64;
    const int lrow = lane & 15, lk = (lane >> 4) * 8;
    const int srow = tid >> 2, skof = (tid & 3) * 8;
    const size_t K_ = (size_t)K;
    const u16* Ag = A + ((size_t)blockIdx.y * 128 + srow) * K_ + skof;
    const u16* Bg = BT + ((size_t)blockIdx.x * 128 + srow) * K_ + skof;
    f32x4 acc[4][4] = {};
    for (int k0 = 0; k0 < K; k0 += 32) {
        uint4 a0 = *(const uint4*)(Ag + k0);
        uint4 a1 = *(const uint4*)(Ag + 64 * K_ + k0);
        uint4 b0 = *(const uint4*)(Bg + k0);
        uint4 b1 = *(const uint4*)(Bg + 64 * K_ + k0);
        __syncthreads();
        *(uint4*)&As[srow][skof]      = a0;
        *(uint4*)&As[srow + 64][skof] = a1;
        *(uint4*)&Bs[srow][skof]      = b0;
        *(uint4*)&Bs[srow + 64][skof] = b1;
        __syncthreads();
        short8 af[4], bf[4];
        #pragma unroll
        for (int i = 0; i < 4; ++i) af[i] = *(const short8*)&As[wm + i * 16 + lrow][lk];
        #pragma unroll
        for (int j = 0; j < 4; ++j) bf[j] = *(const short8*)&Bs[wn + j * 16 + lrow][lk];
        #pragma unroll
        for (int i = 0; i < 4; ++i)
            #pragma unroll
            for (int j = 0; j < 4; ++j)
                acc[i][j] = __builtin_amdgcn_mfma_f32_16x16x32_bf16(af[i], bf[j], acc[i][j], 0, 0, 0);
    }
    const int crow0 = blockIdx.y * 128 + wm + (lane >> 4) * 4;
    const int ccol0 = blockIdx.x * 128 + wn + (lane & 15);
    #pragma unroll
    for (int j = 0; j < 4; ++j) {
        const float bv = bias ? bias[ccol0 + j * 16] : 0.f;
        #pragma unroll
        for (int i = 0; i < 4; ++i)
            #pragma unroll
            for (int rr = 0; rr < 4; ++rr)
                C[(size_t)(crow0 + i * 16 + rr) * N + (ccol0 + j * 16)] = acc[i][j][rr] + bv;
    }
}

// ============ persistent cooperative encoder ============
__global__ __launch_bounds__(512) void enc_coop(
    const float* __restrict__ gx,
    const _Float16* __restrict__ UrzT, const _Float16* __restrict__ UnT,
    const float* __restrict__ brz, const float* __restrict__ bn,
    float* __restrict__ hf32, _Float16* __restrict__ hf16,
    _Float16* __restrict__ rh, float* __restrict__ zb,
    u16* __restrict__ enc_hs, _Float16* __restrict__ spack,
    u32* __restrict__ bar)
{
    const int w = blockIdx.x, tid = threadIdx.x;
    __shared__ __align__(16) _Float16 wlds[78][520];   // >80KB -> 1 WG/CU; rows 0..15 Urz, 16..23 Un
    for (int r = tid >> 6; r < 24; r += 8) {
        const _Float16* src = (r < 16) ? (UrzT + (size_t)(w * 16 + r) * 512)
                                       : (UnT + (size_t)(w * 8 + (r - 16)) * 512);
        const int c64 = tid & 63;
        *(uint4*)&wlds[r][c64 * 8] = *(const uint4*)(src + c64 * 8);
    }
    __syncthreads();
    for (int t = 0; t < SEQ; ++t) {
        {
            const int b = tid >> 4, cl = tid & 15;
            const int g = w * 16 + cl;
            const float a = dot512_lg(&wlds[cl][0], hf16 + b * 512);
            const float gxr = gx[((size_t)(b * SEQ + t)) * 1536 + g];
            if (g < 512) {
                const float r = sigmoid_f(gxr + a + brz[g]);
                rh[b * 512 + g] = (_Float16)(r * hf32[b * 512 + g]);
            } else {
                zb[(g - 512) * 32 + b] = sigmoid_f(gxr + a + brz[g]);
            }
        }
        gbar(bar);
        if (tid < 256) {
            const int b = tid >> 3, cl = tid & 7;
            const int c = w * 8 + cl;
            const float un = dot512_lg(&wlds[16 + cl][0], rh + b * 512);
            const float n = tanh_f(gx[((size_t)(b * SEQ + t)) * 1536 + 1024 + c] + un + bn[c]);
            const float z = zb[c * 32 + b];
            const float hn = (1.f - z) * hf32[b * 512 + c] + z * n;
            hf32[b * 512 + c] = hn;
            hf16[b * 512 + c] = (_Float16)hn;
            enc_hs[(size_t)(b * SEQ + t) * 512 + c] = f2bf(hn);
            spack[(((size_t)b * 16 + (t >> 3)) * 512 + c) * 8 + (t & 7)] = (_Float16)hn;
        }
        gbar(bar);
    }
}

// ============ persistent cooperative decoder ============
__global__ __launch_bounds__(512) void dec_coop(
    const float* __restrict__ gxe, const u16* __restrict__ wh_bf,
    const _Float16* __restrict__ spack,
    const _Float16* __restrict__ UrzT, const _Float16* __restrict__ WsT,
    const _Float16* __restrict__ WxCT, const _Float16* __restrict__ UnT,
    const float* __restrict__ attn_v,
    const float* __restrict__ brz, const float* __restrict__ bn,
    float* __restrict__ hf32, _Float16* __restrict__ hf16,
    _Float16* __restrict__ rh, float* __restrict__ zb, float* __restrict__ gn,
    float* __restrict__ aP, float* __restrict__ aWs,
    _Float16* __restrict__ ctxf, u16* __restrict__ hctx,
    u32* __restrict__ bar)
{
    const int w = blockIdx.x, tid = threadIdx.x;
    __shared__ __align__(16) _Float16 wlds[80][520];   // rows 0..15 Urz,16..23 Ws,24..39 WxC(rz),40..47 WxC(n),48..55 Un
    __shared__ float hWsL[512], avL[512], redE[128];
    __shared__ u32 attnp[64];
    for (int r = tid >> 6; r < 56; r += 8) {
        const _Float16* src;
        if (r < 16)      src = UrzT + (size_t)(w * 16 + r) * 512;
        else if (r < 24) src = WsT + (size_t)(w * 8 + (r - 16)) * 512;
        else if (r < 40) src = WxCT + (size_t)(w * 16 + (r - 24)) * 512;
        else if (r < 48) src = WxCT + (size_t)(1024 + w * 8 + (r - 40)) * 512;
        else             src = UnT + (size_t)(w * 8 + (r - 48)) * 512;
        const int c64 = tid & 63;
        *(uint4*)&wlds[r][c64 * 8] = *(const uint4*)(src + c64 * 8);
    }
    avL[tid & 511] = attn_v[tid & 511];
    __syncthreads();
    for (int t = 0; t < SEQ; ++t) {
        // P1
        {
            const int b = tid >> 4, cl = tid & 15;
            const int g = w * 16 + cl;
            const float a = dot512_lg(&wlds[cl][0], hf16 + b * 512);
            aP[g * 32 + b] = a;
            if (tid < 256) {
                const int b1 = tid >> 3, cl1 = tid & 7;
                const int gs = w * 8 + cl1;
                const float a1 = dot512_lg(&wlds[16 + cl1][0], hf16 + b1 * 512);
                aWs[b1 * 512 + gs] = a1;
            }
        }
        gbar(bar);
        // P2 (attention, WGs 0..31)
        if (w < 32) {
            const int b = w;
            hWsL[tid] = aWs[b * 512 + tid];
            __syncthreads();
            const int s = tid >> 2, q = tid & 3;
            const u16* whr = wh_bf + ((size_t)(b * SEQ + s)) * 512;
            float e = 0.f;
            #pragma unroll 4
            for (int i = 0; i < 16; ++i) {
                const int d = i * 32 + q * 8;
                uint4 wv = *(const uint4*)(whr + d);
                float4 h0 = *(const float4*)&hWsL[d];
                float4 h1 = *(const float4*)&hWsL[d + 4];
                float4 v0 = *(const float4*)&avL[d];
                float4 v1 = *(const float4*)&avL[d + 4];
                e += v0.x * tanh_f(bf2f((u16)(wv.x & 0xFFFF)) + h0.x)
                   + v0.y * tanh_f(bf2f((u16)(wv.x >> 16))    + h0.y)
                   + v0.z * tanh_f(bf2f((u16)(wv.y & 0xFFFF)) + h0.z)
                   + v0.w * tanh_f(bf2f((u16)(wv.y >> 16))    + h0.w)
                   + v1.x * tanh_f(bf2f((u16)(wv.z & 0xFFFF)) + h1.x)
                   + v1.y * tanh_f(bf2f((u16)(wv.z >> 16))    + h1.y)
                   + v1.z * tanh_f(bf2f((u16)(wv.w & 0xFFFF)) + h1.z)
                   + v1.w * tanh_f(bf2f((u16)(wv.w >> 16))    + h1.w);
            }
            e += __shfl_xor(e, 1); e += __shfl_xor(e, 2);
            if (q == 0) redE[s] = e;
            __syncthreads();
            if (tid < 64) {
                float e0 = redE[tid], e1 = redE[tid + 64];
                float m = fmaxf(e0, e1);
                for (int o = 32; o >= 1; o >>= 1) m = fmaxf(m, __shfl_xor(m, o));
                float p0 = fexp2((e0 - m) * 1.442695040888963f);
                float p1 = fexp2((e1 - m) * 1.442695040888963f);
                float ss = p0 + p1;
                for (int o = 32; o >= 1; o >>= 1) ss += __shfl_xor(ss, o);
                const float inv = frcp(ss);
                ((u16*)attnp)[tid]      = __builtin_bit_cast(u16, (_Float16)(p0 * inv));
                ((u16*)attnp)[tid + 64] = __builtin_bit_cast(u16, (_Float16)(p1 * inv));
            }
            __syncthreads();
            {
                float cv = 0.f;
                const _Float16* sp = spack + (((size_t)b * 16) * 512 + tid) * 8;
                #pragma unroll 4
                for (int sb = 0; sb < 16; ++sb) {
                    uint4 sv = *(const uint4*)(sp + (size_t)sb * 4096);
                    uint4 ap = *(const uint4*)&attnp[sb * 4];
                    dot4x(cv, sv, ap);
                }
                ctxf[b * 512 + tid] = (_Float16)cv;
                hctx[((size_t)(b * SEQ + t)) * 1024 + 512 + tid] = f2bf(cv);
            }
        }
        gbar(bar);
        // P3
        {
            const int b = tid >> 4, cl = tid & 15;
            const int g = w * 16 + cl;
            const float a = dot512_lg(&wlds[24 + cl][0], ctxf + b * 512);
            const float gxr = gxe[((size_t)(b * SEQ + t)) * 1536 + g];
            if (g < 512) {
                const float r = sigmoid_f(gxr + a + aP[g * 32 + b] + brz[g]);
                rh[b * 512 + g] = (_Float16)(r * hf32[b * 512 + g]);
            } else {
                zb[(g - 512) * 32 + b] = sigmoid_f(gxr + a + aP[g * 32 + b] + brz[g]);
            }
            if (tid < 256) {
                const int b1 = tid >> 3, cl1 = tid & 7;
                const int g3 = 1024 + w * 8 + cl1;
                const float a1 = dot512_lg(&wlds[40 + cl1][0], ctxf + b1 * 512);
                gn[(g3 - 1024) * 32 + b1] = gxe[((size_t)(b1 * SEQ + t)) * 1536 + g3] + a1;
            }
        }
        gbar(bar);
        // P4
        if (tid < 256) {
            const int b = tid >> 3, cl = tid & 7;
            const int c = w * 8 + cl;
            const float un = dot512_lg(&wlds[48 + cl][0], rh + b * 512);
            const float n = tanh_f(gn[c * 32 + b] + un + bn[c]);
            const float z = zb[c * 32 + b];
            const float hn = (1.f - z) * hf32[b * 512 + c] + z * n;
            hf32[b * 512 + c] = hn;
            hf16[b * 512 + c] = (_Float16)hn;
            hctx[((size_t)(b * SEQ + t)) * 1024 + c] = f2bf(hn);
        }
        gbar(bar);
    }
}

// ---------------- log_softmax ----------------
__global__ __launch_bounds__(256) void log_softmax_rows(float* __restrict__ out)
{
    const int row = blockIdx.x, tid = threadIdx.x;
    float* p = out + (size_t)row * VTOK;
    __shared__ float rb[4];
    float m = -3.0e38f;
    for (int i = tid * 4; i < VTOK; i += 1024) {
        float4 v = *(const float4*)(p + i);
        m = fmaxf(m, fmaxf(fmaxf(v.x, v.y), fmaxf(v.z, v.w)));
    }
    for (int o = 32; o >= 1; o >>= 1) m = fmaxf(m, __shfl_xor(m, o));
    if ((tid & 63) == 0) rb[tid >> 6] = m;
    __syncthreads();
    m = fmaxf(fmaxf(rb[0], rb[1]), fmaxf(rb[2], rb[3]));
    float s = 0.f;
    for (int i = tid * 4; i < VTOK; i += 1024) {
        float4 v = *(const float4*)(p + i);
        s += fexp2((v.x - m) * 1.442695040888963f) + fexp2((v.y - m) * 1.442695040888963f)
           + fexp2((v.z - m) * 1.442695040888963f) + fexp2((v.w - m) * 1.442695040888963f);
    }
    for (int o = 32; o >= 1; o >>= 1) s += __shfl_xor(s, o);
    __syncthreads();
    if ((tid & 63) == 0) rb[tid >> 6] = s;
    __syncthreads();
    s = rb[0] + rb[1] + rb[2] + rb[3];
    const float lse = m + __builtin_amdgcn_logf(s) * 0.6931471805599453f;
    for (int i = tid * 4; i < VTOK; i += 1024) {
        float4 v = *(const float4*)(p + i);
        v.x -= lse; v.y -= lse; v.z -= lse; v.w -= lse;
        *(float4*)(p + i) = v;
    }
}

// ---------------- host launcher ----------------
extern "C" void kernel_launch(void* const* d_in, const int* in_sizes, int n_in,
                              void* d_out, int out_size, void* d_ws, size_t ws_size,
                              hipStream_t stream)
{
    (void)in_sizes; (void)n_in; (void)out_size; (void)ws_size;
    const int*   src       = (const int*)  d_in[0];
    const int*   tgt       = (const int*)  d_in[1];
    const float* enc_embed = (const float*)d_in[2];
    const float* enc_Wx    = (const float*)d_in[3];
    const float* enc_bx    = (const float*)d_in[4];
    const float* enc_Urz   = (const float*)d_in[5];
    const float* enc_brz   = (const float*)d_in[6];
    const float* enc_Un    = (const float*)d_in[7];
    const float* enc_bn    = (const float*)d_in[8];
    const float* dec_embed = (const float*)d_in[9];
    const float* dec_Wx    = (const float*)d_in[10];
    const float* dec_bx    = (const float*)d_in[11];
    const float* dec_Urz   = (const float*)d_in[12];
    const float* dec_brz   = (const float*)d_in[13];
    const float* dec_Un    = (const float*)d_in[14];
    const float* dec_bn    = (const float*)d_in[15];
    const float* attn_Wh   = (const float*)d_in[16];
    const float* attn_Ws   = (const float*)d_in[17];
    const float* attn_v    = (const float*)d_in[18];
    const float* out_W     = (const float*)d_in[19];
    const float* out_b     = (const float*)d_in[20];

    char* ob = (char*)d_out;
    float*    gx_enc  = (float*)   (ob + 0);
    float*    gxe_dec = (float*)   (ob + 25165824);
    float*    wh_enc  = (float*)   (ob + 50331648);
    u16*      Aenc    = (u16*)     (ob + 58720256);
    u16*      Adec    = (u16*)     (ob + 62914560);
    u16*      enc_hs  = (u16*)     (ob + 67108864);
    _Float16* spack   = (_Float16*)(ob + 71303168);
    u16*      wh_bf   = (u16*)     (ob + 75497472);
    u16*      encWxT  = (u16*)     (ob + 79691776);
    u16*      decWxET = (u16*)     (ob + 81264640);
    u16*      WhT     = (u16*)     (ob + 82837504);
    _Float16* UrzET   = (_Float16*)(ob + 83361792);
    _Float16* UnET    = (_Float16*)(ob + 84410368);
    _Float16* UrzDT   = (_Float16*)(ob + 84934656);
    _Float16* UnDT    = (_Float16*)(ob + 85983232);
    _Float16* WsT     = (_Float16*)(ob + 86507520);
    _Float16* WxCT    = (_Float16*)(ob + 87031808);
    float*    hf32    = (float*)   (ob + 88604672);
    _Float16* hf16    = (_Float16*)(ob + 88670208);
    _Float16* rh_f16  = (_Float16*)(ob + 88702976);
    float*    zbuf    = (float*)   (ob + 88735744);
    float*    gnD     = (float*)   (ob + 88801280);
    float*    aP      = (float*)   (ob + 88866816);
    float*    aWs     = (float*)   (ob + 88997888);
    _Float16* ctxf    = (_Float16*)(ob + 89063424);
    u32*      barp    = (u32*)     (ob + 89096192);

    char* wb = (char*)d_ws;
    u16* outWT = (u16*)(wb + 0);
    u16* hctx  = (u16*)(wb + 65536000);

    transpose_cvt<<<dim3(48, 16),   256, 0, stream>>>(enc_Wx,  encWxT, 512, 1536);
    transpose_cvt<<<dim3(48, 16),   256, 0, stream>>>(dec_Wx,  decWxET,512, 1536);
    transpose_cvt<<<dim3(16, 16),   256, 0, stream>>>(attn_Wh, WhT,    512, 512);
    transpose_cvt<<<dim3(1000, 32), 256, 0, stream>>>(out_W,   outWT, 1024, 32000);
    transpose_cvt_f16<<<dim3(32, 16), 256, 0, stream>>>(enc_Urz, UrzET, 512, 1024);
    transpose_cvt_f16<<<dim3(16, 16), 256, 0, stream>>>(enc_Un,  UnET,  512, 512);
    transpose_cvt_f16<<<dim3(32, 16), 256, 0, stream>>>(dec_Urz, UrzDT, 512, 1024);
    transpose_cvt_f16<<<dim3(16, 16), 256, 0, stream>>>(dec_Un,  UnDT,  512, 512);
    transpose_cvt_f16<<<dim3(16, 16), 256, 0, stream>>>(attn_Ws, WsT,   512, 512);
    transpose_cvt_f16<<<dim3(48, 16), 256, 0, stream>>>(dec_Wx + (size_t)512 * 1536, WxCT, 512, 1536);
    gather_emb_bf16<<<4096, 128, 0, stream>>>(src, enc_embed, Aenc);
    gather_emb_bf16<<<4096, 128, 0, stream>>>(tgt, dec_embed, Adec);

    gemm_bf16<<<dim3(12, 32), 256, 0, stream>>>(Aenc, encWxT,  enc_bx, gx_enc,  4096, 1536, 512);
    gemm_bf16<<<dim3(12, 32), 256, 0, stream>>>(Adec, decWxET, dec_bx, gxe_dec, 4096, 1536, 512);

    init_state<<<32, 512, 0, stream>>>(hf32, hf16, barp);

    {
        void* args[] = { (void*)&gx_enc, (void*)&UrzET, (void*)&UnET, (void*)&enc_brz,
                         (void*)&enc_bn, (void*)&hf32, (void*)&hf16, (void*)&rh_f16,
                         (void*)&zbuf, (void*)&enc_hs, (void*)&spack, (void*)&barp };
        hipLaunchCooperativeKernel((void*)enc_coop, dim3(NWG), dim3(512), args, 0, stream);
    }

    gemm_bf16<<<dim3(4, 32), 256, 0, stream>>>(enc_hs, WhT, nullptr, wh_enc, 4096, 512, 512);
    cvt_f32_bf16<<<1024, 256, 0, stream>>>(wh_enc, wh_bf);

    {
        void* args[] = { (void*)&gxe_dec, (void*)&wh_bf, (void*)&spack, (void*)&UrzDT,
                         (void*)&WsT, (void*)&WxCT, (void*)&UnDT, (void*)&attn_v,
                         (void*)&dec_brz, (void*)&dec_bn, (void*)&hf32, (void*)&hf16,
                         (void*)&rh_f16, (void*)&zbuf, (void*)&gnD, (void*)&aP, (void*)&aWs,
                         (void*)&ctxf, (void*)&hctx, (void*)&barp };
        hipLaunchCooperativeKernel((void*)dec_coop, dim3(NWG), dim3(512), args, 0, stream);
    }

    gemm_bf16<<<dim3(250, 32), 256, 0, stream>>>(hctx, outWT, out_b, (float*)d_out, 4096, VTOK, 1024);
    log_softmax_rows<<<4096, 256, 0, stream>>>((float*)d_out);
}

// Round 6
// 6832.327 us; speedup vs baseline: 2.2374x; 1.6164x over previous
//
#include <hip/hip_runtime.h>
#include <stdint.h>

#define BATCH 32
#define SEQ   128       // S == T == 128
#define HID   512
#define VTOK  32000

typedef unsigned short u16;
typedef unsigned int   u32;
typedef unsigned long long u64;
typedef float    f32x4  __attribute__((ext_vector_type(4)));
typedef short    short8 __attribute__((ext_vector_type(8)));

__device__ __forceinline__ u16 f2bf(float f) {
    u32 u = __builtin_bit_cast(u32, f);
    return (u16)((u + 0x7FFFu + ((u >> 16) & 1u)) >> 16);
}
__device__ __forceinline__ float bf2f(u16 v) {
    u32 u = ((u32)v) << 16; return __builtin_bit_cast(float, u);
}
__device__ __forceinline__ float fexp2(float x) { return __builtin_amdgcn_exp2f(x); }
__device__ __forceinline__ float frcp(float x)  { return __builtin_amdgcn_rcpf(x); }
__device__ __forceinline__ float sigmoid_f(float x) {
    return frcp(1.f + fexp2(-1.442695040888963f * x));
}
__device__ __forceinline__ float tanh_f(float x) {
    return 1.f - 2.f * frcp(1.f + fexp2(2.885390081777927f * x));
}

// ---- LLC-coherent (sc1) relaxed atomics: no wbl2/inv cache maintenance ----
__device__ __forceinline__ u32 ld_sc1_u32(const u32* p) {
    return __hip_atomic_load(p, __ATOMIC_RELAXED, __HIP_MEMORY_SCOPE_AGENT);
}
__device__ __forceinline__ void st_sc1_u32(u32* p, u32 v) {
    __hip_atomic_store(p, v, __ATOMIC_RELAXED, __HIP_MEMORY_SCOPE_AGENT);
}
__device__ __forceinline__ u64 ld_sc1_u64(const u64* p) {
    return __hip_atomic_load(p, __ATOMIC_RELAXED, __HIP_MEMORY_SCOPE_AGENT);
}
// A-fragment (8 bf16) from an sc1-coherent row-major [b][512] bf16 buffer
__device__ __forceinline__ short8 ldA(const u64* base) {
    union { u64 q[2]; short8 s; } u;
    u.q[0] = ld_sc1_u64(base);
    u.q[1] = ld_sc1_u64(base + 1);
    return u.s;
}

// ---- fence-free grid barrier: monotonic count + gen, relaxed sc1 atomics ----
// Each wave drains its own (sc1) stores via vmcnt(0) BEFORE syncthreads, so by
// the time thread 0 arrives, all of this WG's data is at the LLC.
__device__ __forceinline__ void gbar(u32* bar, u32 nwg) {
    asm volatile("s_waitcnt vmcnt(0)" ::: "memory");
    __syncthreads();
    if (threadIdx.x == 0) {
        u32 a = __hip_atomic_fetch_add(bar, 1u, __ATOMIC_RELAXED, __HIP_MEMORY_SCOPE_AGENT);
        u32 tgt = a / nwg + 1u;
        if (a % nwg == nwg - 1u) {
            __hip_atomic_store(bar + 32, tgt, __ATOMIC_RELAXED, __HIP_MEMORY_SCOPE_AGENT);
        } else {
            while (__hip_atomic_load(bar + 32, __ATOMIC_RELAXED, __HIP_MEMORY_SCOPE_AGENT) < tgt)
                __builtin_amdgcn_s_sleep(4);
        }
        asm volatile("" ::: "memory");
    }
    __syncthreads();
}

// ---------------- prep kernels ----------------

// f32 [K,N] -> bf16 [N,K]
__global__ __launch_bounds__(256) void transpose_cvt(
    const float* __restrict__ src, u16* __restrict__ dst, int K, int N)
{
    __shared__ float tile[32][33];
    const int n0 = blockIdx.x * 32, k0 = blockIdx.y * 32;
    const int tx = threadIdx.x & 31, ty = threadIdx.x >> 5;
    #pragma unroll
    for (int j = 0; j < 32; j += 8)
        tile[ty + j][tx] = src[(size_t)(k0 + ty + j) * N + n0 + tx];
    __syncthreads();
    #pragma unroll
    for (int j = 0; j < 32; j += 8)
        dst[(size_t)(n0 + ty + j) * K + k0 + tx] = f2bf(tile[tx][ty + j]);
}

__global__ __launch_bounds__(256) void cvt_f32_bf16(
    const float* __restrict__ src, u16* __restrict__ dst)
{
    const size_t i = ((size_t)blockIdx.x * 256 + threadIdx.x) * 8;
    float4 v0 = *(const float4*)(src + i);
    float4 v1 = *(const float4*)(src + i + 4);
    uint4 pk;
    pk.x = (u32)f2bf(v0.x) | ((u32)f2bf(v0.y) << 16);
    pk.y = (u32)f2bf(v0.z) | ((u32)f2bf(v0.w) << 16);
    pk.z = (u32)f2bf(v1.x) | ((u32)f2bf(v1.y) << 16);
    pk.w = (u32)f2bf(v1.z) | ((u32)f2bf(v1.w) << 16);
    *(uint4*)(dst + i) = pk;
}

__global__ __launch_bounds__(128) void gather_emb_bf16(
    const int* __restrict__ idx, const float* __restrict__ emb, u16* __restrict__ out)
{
    const int r = blockIdx.x;
    const int token = idx[r];
    const int i = threadIdx.x * 4;
    float4 v = *(const float4*)(emb + (size_t)token * 512 + i);
    uint2 pk;
    pk.x = (u32)f2bf(v.x) | ((u32)f2bf(v.y) << 16);
    pk.y = (u32)f2bf(v.z) | ((u32)f2bf(v.w) << 16);
    *(uint2*)(out + (size_t)r * 512 + i) = pk;
}

// zero h (8192 u32) + both barrier blocks (128 u32)
__global__ __launch_bounds__(512) void init_state(u32* hg, u32* bar)
{
    const int i = blockIdx.x * 512 + threadIdx.x;
    hg[i] = 0u;
    if (blockIdx.x == 0 && threadIdx.x < 128) bar[threadIdx.x] = 0u;
}

// ---------------- MFMA GEMM:  C[M,N](f32) = A[M,K](bf16) * BT[N,K](bf16) + bias ----------------
__global__ __launch_bounds__(256) void gemm_bf16(
    const u16* __restrict__ A, const u16* __restrict__ BT,
    const float* __restrict__ bias, float* __restrict__ C,
    int M, int N, int K)
{
    __shared__ __align__(16) u16 As[128][40];
    __shared__ __align__(16) u16 Bs[128][40];
    const int tid  = threadIdx.x;
    const int lane = tid & 63, wave = tid >> 6;
    const int wm = (wave & 1) * 64, wn = (wave >> 1) * 64;
    const int lrow = lane & 15, lk = (lane >> 4) * 8;
    const int srow = tid >> 2, skof = (tid & 3) * 8;
    const size_t K_ = (size_t)K;
    const u16* Ag = A + ((size_t)blockIdx.y * 128 + srow) * K_ + skof;
    const u16* Bg = BT + ((size_t)blockIdx.x * 128 + srow) * K_ + skof;
    f32x4 acc[4][4] = {};
    for (int k0 = 0; k0 < K; k0 += 32) {
        uint4 a0 = *(const uint4*)(Ag + k0);
        uint4 a1 = *(const uint4*)(Ag + 64 * K_ + k0);
        uint4 b0 = *(const uint4*)(Bg + k0);
        uint4 b1 = *(const uint4*)(Bg + 64 * K_ + k0);
        __syncthreads();
        *(uint4*)&As[srow][skof]      = a0;
        *(uint4*)&As[srow + 64][skof] = a1;
        *(uint4*)&Bs[srow][skof]      = b0;
        *(uint4*)&Bs[srow + 64][skof] = b1;
        __syncthreads();
        short8 af[4], bf[4];
        #pragma unroll
        for (int i = 0; i < 4; ++i) af[i] = *(const short8*)&As[wm + i * 16 + lrow][lk];
        #pragma unroll
        for (int j = 0; j < 4; ++j) bf[j] = *(const short8*)&Bs[wn + j * 16 + lrow][lk];
        #pragma unroll
        for (int i = 0; i < 4; ++i)
            #pragma unroll
            for (int j = 0; j < 4; ++j)
                acc[i][j] = __builtin_amdgcn_mfma_f32_16x16x32_bf16(af[i], bf[j], acc[i][j], 0, 0, 0);
    }
    const int crow0 = blockIdx.y * 128 + wm + (lane >> 4) * 4;
    const int ccol0 = blockIdx.x * 128 + wn + (lane & 15);
    #pragma unroll
    for (int j = 0; j < 4; ++j) {
        const float bv = bias ? bias[ccol0 + j * 16] : 0.f;
        #pragma unroll
        for (int i = 0; i < 4; ++i)
            #pragma unroll
            for (int rr = 0; rr < 4; ++rr)
                C[(size_t)(crow0 + i * 16 + rr) * N + (ccol0 + j * 16)] = acc[i][j][rr] + bv;
    }
}

// ============ persistent cooperative encoder: 64 WGs, MFMA phases, sc1 comm ============
// cross-WG buffers (all bf16-pair u32 or f32 u32, sc1): hg[b][256], rhg[b][256], zg[n'][32]
__global__ __launch_bounds__(512) void enc_coop(
    const float* __restrict__ gx, const u16* __restrict__ Urz, const u16* __restrict__ Un,
    const float* __restrict__ brz, const float* __restrict__ bn,
    u32* __restrict__ hg, u32* __restrict__ rhg, u32* __restrict__ zg,
    u16* __restrict__ enc_hs, u16* __restrict__ spack, u32* __restrict__ bar)
{
    const int w = blockIdx.x, tid = threadIdx.x;
    const int v = tid >> 6, lane = tid & 63;
    const int nl = lane & 15, kq = lane >> 4;
    const u64* hq = (const u64*)hg;
    const u64* rq = (const u64*)rhg;
    for (int t = 0; t < SEQ; ++t) {
        // ---- E1: [32,512]x[512,1024] h@Urz; waves 0,1 (bt) per WG; n-tile = w ----
        if (v < 2) {
            const int bt = v;
            const int n = w * 16 + nl;
            const int brow = bt * 16 + nl;
            const u16* wp = Urz + (size_t)n * 512 + kq * 8;
            f32x4 acc = {0.f, 0.f, 0.f, 0.f};
            #pragma unroll
            for (int k0 = 0; k0 < 512; k0 += 32) {
                short8 af = ldA(hq + brow * 128 + (k0 >> 2) + kq * 2);
                short8 bf = *(const short8*)(wp + k0);
                acc = __builtin_amdgcn_mfma_f32_16x16x32_bf16(af, bf, acc, 0, 0, 0);
            }
            if (n < 512) {               // r gate -> rh
                u32 pk[4];
                #pragma unroll
                for (int rr = 0; rr < 4; ++rr) {
                    const int b = bt * 16 + kq * 4 + rr;
                    const float gxr = gx[((size_t)(b * SEQ + t)) * 1536 + n];
                    const float r = sigmoid_f(gxr + acc[rr] + brz[n]);
                    u32 hv = ld_sc1_u32(hg + b * 256 + (n >> 1));
                    const float hold = bf2f((u16)((n & 1) ? (hv >> 16) : (hv & 0xFFFF)));
                    pk[rr] = (u32)f2bf(r * hold);
                }
                #pragma unroll
                for (int rr = 0; rr < 4; ++rr) {
                    u32 oth = (u32)__shfl_xor((int)pk[rr], 1);
                    if ((n & 1) == 0) {
                        const int b = bt * 16 + kq * 4 + rr;
                        st_sc1_u32(rhg + b * 256 + (n >> 1), (pk[rr] & 0xFFFF) | (oth << 16));
                    }
                }
            } else {                     // z gate
                #pragma unroll
                for (int rr = 0; rr < 4; ++rr) {
                    const int b = bt * 16 + kq * 4 + rr;
                    const float gxr = gx[((size_t)(b * SEQ + t)) * 1536 + n];
                    const float z = sigmoid_f(gxr + acc[rr] + brz[n]);
                    st_sc1_u32(zg + (n - 512) * 32 + b, __float_as_uint(z));
                }
            }
        }
        gbar(bar, 64u);
        // ---- E2: (r*h)@Un, h update ----
        if (v < 2 && w < 32) {
            const int bt = v;
            const int n = w * 16 + nl;
            const int brow = bt * 16 + nl;
            const u16* wp = Un + (size_t)n * 512 + kq * 8;
            f32x4 acc = {0.f, 0.f, 0.f, 0.f};
            #pragma unroll
            for (int k0 = 0; k0 < 512; k0 += 32) {
                short8 af = ldA(rq + brow * 128 + (k0 >> 2) + kq * 2);
                short8 bf = *(const short8*)(wp + k0);
                acc = __builtin_amdgcn_mfma_f32_16x16x32_bf16(af, bf, acc, 0, 0, 0);
            }
            u32 pk[4];
            #pragma unroll
            for (int rr = 0; rr < 4; ++rr) {
                const int b = bt * 16 + kq * 4 + rr;
                const float gxr = gx[((size_t)(b * SEQ + t)) * 1536 + 1024 + n];
                const float nn = tanh_f(gxr + acc[rr] + bn[n]);
                const float z = __uint_as_float(ld_sc1_u32(zg + n * 32 + b));
                u32 hv = ld_sc1_u32(hg + b * 256 + (n >> 1));
                const float hold = bf2f((u16)((n & 1) ? (hv >> 16) : (hv & 0xFFFF)));
                const float hn = (1.f - z) * hold + z * nn;
                const u16 hb = f2bf(hn);
                pk[rr] = (u32)hb;
                enc_hs[((size_t)(b * SEQ + t)) * 512 + n] = hb;
                spack[(((size_t)b * 16 + (t >> 3)) * 512 + n) * 8 + (t & 7)] = hb;
            }
            #pragma unroll
            for (int rr = 0; rr < 4; ++rr) {
                u32 oth = (u32)__shfl_xor((int)pk[rr], 1);
                if ((n & 1) == 0) {
                    const int b = bt * 16 + kq * 4 + rr;
                    st_sc1_u32(hg + b * 256 + (n >> 1), (pk[rr] & 0xFFFF) | (oth << 16));
                }
            }
        }
        gbar(bar, 64u);
    }
}

// ============ persistent cooperative decoder: 96 WGs, MFMA phases, sc1 comm ============
__global__ __launch_bounds__(512) void dec_coop(
    const float* __restrict__ gxe, const u16* __restrict__ wh_bf, const u16* __restrict__ spack,
    const float* __restrict__ attn_v, const float* __restrict__ brz, const float* __restrict__ bn,
    const u16* __restrict__ Urz, const u16* __restrict__ Ws,
    const u16* __restrict__ WxC, const u16* __restrict__ Un,
    u32* __restrict__ hg, u32* __restrict__ rhg, u32* __restrict__ ctxg,
    u32* __restrict__ zg, u32* __restrict__ gg, u32* __restrict__ aWsg,
    u16* __restrict__ hctx, u32* __restrict__ bar)
{
    const int w = blockIdx.x, tid = threadIdx.x;
    const int v = tid >> 6, lane = tid & 63;
    const int nl = lane & 15, kq = lane >> 4;
    __shared__ float hWsL[512], redE[512], attnL[128];
    __shared__ u16 ctxL[512];
    const u64* hq = (const u64*)hg;
    const u64* rq = (const u64*)rhg;
    const u64* cq = (const u64*)ctxg;
    for (int t = 0; t < SEQ; ++t) {
        f32x4 aPk = {0.f, 0.f, 0.f, 0.f};
        // ---- P1: h@[Urz | Ws]; n = w*16+nl in [0,1536) ----
        if (v < 2) {
            const int bt = v;
            const int n = w * 16 + nl;
            const int brow = bt * 16 + nl;
            const u16* wp = (n < 1024 ? Urz + (size_t)n * 512
                                      : Ws + (size_t)(n - 1024) * 512) + kq * 8;
            f32x4 acc = {0.f, 0.f, 0.f, 0.f};
            #pragma unroll
            for (int k0 = 0; k0 < 512; k0 += 32) {
                short8 af = ldA(hq + brow * 128 + (k0 >> 2) + kq * 2);
                short8 bf = *(const short8*)(wp + k0);
                acc = __builtin_amdgcn_mfma_f32_16x16x32_bf16(af, bf, acc, 0, 0, 0);
            }
            if (n < 1024) {
                aPk = acc;               // registers persist to P3 (same lane owns same (n,b))
            } else {
                #pragma unroll
                for (int rr = 0; rr < 4; ++rr) {
                    const int b = bt * 16 + kq * 4 + rr;
                    st_sc1_u32(aWsg + (n - 1024) * 32 + b, __float_as_uint(acc[rr]));
                }
            }
        }
        gbar(bar, 96u);
        // ---- P2: attention, WG b = w < 32 (whole WG) ----
        if (w < 32) {
            const int b = w;
            hWsL[tid] = __uint_as_float(ld_sc1_u32(aWsg + tid * 32 + b));
            __syncthreads();
            {
                const int s = tid >> 2, q = tid & 3;
                const u16* whr = wh_bf + ((size_t)(b * SEQ + s)) * 512 + q * 128;
                const float* avq = attn_v + q * 128;
                const float* hwq = &hWsL[q * 128];
                float e = 0.f;
                #pragma unroll 4
                for (int i = 0; i < 128; i += 8) {
                    uint4 wv = *(const uint4*)(whr + i);
                    float4 h0 = *(const float4*)(hwq + i);
                    float4 h1 = *(const float4*)(hwq + i + 4);
                    float4 v0 = *(const float4*)(avq + i);
                    float4 v1 = *(const float4*)(avq + i + 4);
                    e += v0.x * tanh_f(bf2f((u16)(wv.x & 0xFFFF)) + h0.x)
                       + v0.y * tanh_f(bf2f((u16)(wv.x >> 16))    + h0.y)
                       + v0.z * tanh_f(bf2f((u16)(wv.y & 0xFFFF)) + h0.z)
                       + v0.w * tanh_f(bf2f((u16)(wv.y >> 16))    + h0.w)
                       + v1.x * tanh_f(bf2f((u16)(wv.z & 0xFFFF)) + h1.x)
                       + v1.y * tanh_f(bf2f((u16)(wv.z >> 16))    + h1.y)
                       + v1.z * tanh_f(bf2f((u16)(wv.w & 0xFFFF)) + h1.z)
                       + v1.w * tanh_f(bf2f((u16)(wv.w >> 16))    + h1.w);
                }
                redE[tid] = e;
            }
            __syncthreads();
            if (tid < 64) {
                float e0 = redE[4 * tid] + redE[4 * tid + 1] + redE[4 * tid + 2] + redE[4 * tid + 3];
                float e1 = redE[4 * (tid + 64)] + redE[4 * (tid + 64) + 1]
                         + redE[4 * (tid + 64) + 2] + redE[4 * (tid + 64) + 3];
                float m = fmaxf(e0, e1);
                for (int o = 32; o >= 1; o >>= 1) m = fmaxf(m, __shfl_xor(m, o));
                float p0 = fexp2((e0 - m) * 1.442695040888963f);
                float p1 = fexp2((e1 - m) * 1.442695040888963f);
                float ss = p0 + p1;
                for (int o = 32; o >= 1; o >>= 1) ss += __shfl_xor(ss, o);
                const float inv = frcp(ss);
                attnL[tid]      = p0 * inv;
                attnL[tid + 64] = p1 * inv;
            }
            __syncthreads();
            {
                const int d = tid;
                float cv = 0.f;
                const u16* sp = spack + ((size_t)b * 16 * 512 + d) * 8;
                #pragma unroll 4
                for (int sb = 0; sb < 16; ++sb) {
                    uint4 sv = *(const uint4*)(sp + (size_t)sb * 4096);
                    const float* al = &attnL[sb * 8];
                    cv += al[0] * bf2f((u16)(sv.x & 0xFFFF)) + al[1] * bf2f((u16)(sv.x >> 16))
                        + al[2] * bf2f((u16)(sv.y & 0xFFFF)) + al[3] * bf2f((u16)(sv.y >> 16))
                        + al[4] * bf2f((u16)(sv.z & 0xFFFF)) + al[5] * bf2f((u16)(sv.z >> 16))
                        + al[6] * bf2f((u16)(sv.w & 0xFFFF)) + al[7] * bf2f((u16)(sv.w >> 16));
                }
                const u16 cb = f2bf(cv);
                ctxL[d] = cb;
                hctx[((size_t)(b * SEQ + t)) * 1024 + 512 + d] = cb;
            }
            __syncthreads();
            if (tid < 256) {
                u32 pk = (u32)ctxL[2 * tid] | ((u32)ctxL[2 * tid + 1] << 16);
                st_sc1_u32(ctxg + b * 256 + tid, pk);
            }
        }
        gbar(bar, 96u);
        // ---- P3: ctx@WxC + gates (aPk from P1 in regs) ----
        if (v < 2) {
            const int bt = v;
            const int n = w * 16 + nl;
            const int brow = bt * 16 + nl;
            const u16* wp = WxC + (size_t)n * 512 + kq * 8;
            f32x4 acc = {0.f, 0.f, 0.f, 0.f};
            #pragma unroll
            for (int k0 = 0; k0 < 512; k0 += 32) {
                short8 af = ldA(cq + brow * 128 + (k0 >> 2) + kq * 2);
                short8 bf = *(const short8*)(wp + k0);
                acc = __builtin_amdgcn_mfma_f32_16x16x32_bf16(af, bf, acc, 0, 0, 0);
            }
            if (n < 512) {               // r gate -> rh
                u32 pk[4];
                #pragma unroll
                for (int rr = 0; rr < 4; ++rr) {
                    const int b = bt * 16 + kq * 4 + rr;
                    const float gxr = gxe[((size_t)(b * SEQ + t)) * 1536 + n];
                    const float r = sigmoid_f(gxr + acc[rr] + aPk[rr] + brz[n]);
                    u32 hv = ld_sc1_u32(hg + b * 256 + (n >> 1));
                    const float hold = bf2f((u16)((n & 1) ? (hv >> 16) : (hv & 0xFFFF)));
                    pk[rr] = (u32)f2bf(r * hold);
                }
                #pragma unroll
                for (int rr = 0; rr < 4; ++rr) {
                    u32 oth = (u32)__shfl_xor((int)pk[rr], 1);
                    if ((n & 1) == 0) {
                        const int b = bt * 16 + kq * 4 + rr;
                        st_sc1_u32(rhg + b * 256 + (n >> 1), (pk[rr] & 0xFFFF) | (oth << 16));
                    }
                }
            } else if (n < 1024) {       // z gate
                #pragma unroll
                for (int rr = 0; rr < 4; ++rr) {
                    const int b = bt * 16 + kq * 4 + rr;
                    const float gxr = gxe[((size_t)(b * SEQ + t)) * 1536 + n];
                    const float z = sigmoid_f(gxr + acc[rr] + aPk[rr] + brz[n]);
                    st_sc1_u32(zg + (n - 512) * 32 + b, __float_as_uint(z));
                }
            } else {                     // n-gate pre-activation (un + bn added in P4)
                #pragma unroll
                for (int rr = 0; rr < 4; ++rr) {
                    const int b = bt * 16 + kq * 4 + rr;
                    const float gxr = gxe[((size_t)(b * SEQ + t)) * 1536 + n];
                    st_sc1_u32(gg + (n - 1024) * 32 + b, __float_as_uint(gxr + acc[rr]));
                }
            }
        }
        gbar(bar, 96u);
        // ---- P4: (r*h)@Un, h update ----
        if (v < 2 && w < 32) {
            const int bt = v;
            const int n = w * 16 + nl;
            const int brow = bt * 16 + nl;
            const u16* wp = Un + (size_t)n * 512 + kq * 8;
            f32x4 acc = {0.f, 0.f, 0.f, 0.f};
            #pragma unroll
            for (int k0 = 0; k0 < 512; k0 += 32) {
                short8 af = ldA(rq + brow * 128 + (k0 >> 2) + kq * 2);
                short8 bf = *(const short8*)(wp + k0);
                acc = __builtin_amdgcn_mfma_f32_16x16x32_bf16(af, bf, acc, 0, 0, 0);
            }
            u32 pk[4];
            #pragma unroll
            for (int rr = 0; rr < 4; ++rr) {
                const int b = bt * 16 + kq * 4 + rr;
                const float gnv = __uint_as_float(ld_sc1_u32(gg + n * 32 + b));
                const float nn = tanh_f(gnv + acc[rr] + bn[n]);
                const float z = __uint_as_float(ld_sc1_u32(zg + n * 32 + b));
                u32 hv = ld_sc1_u32(hg + b * 256 + (n >> 1));
                const float hold = bf2f((u16)((n & 1) ? (hv >> 16) : (hv & 0xFFFF)));
                const float hn = (1.f - z) * hold + z * nn;
                const u16 hb = f2bf(hn);
                pk[rr] = (u32)hb;
                hctx[((size_t)(b * SEQ + t)) * 1024 + n] = hb;
            }
            #pragma unroll
            for (int rr = 0; rr < 4; ++rr) {
                u32 oth = (u32)__shfl_xor((int)pk[rr], 1);
                if ((n & 1) == 0) {
                    const int b = bt * 16 + kq * 4 + rr;
                    st_sc1_u32(hg + b * 256 + (n >> 1), (pk[rr] & 0xFFFF) | (oth << 16));
                }
            }
        }
        gbar(bar, 96u);
    }
}

// ---------------- log_softmax per row, in-place on [4096, 32000] ----------------
__global__ __launch_bounds__(256) void log_softmax_rows(float* __restrict__ out)
{
    const int row = blockIdx.x, tid = threadIdx.x;
    float* p = out + (size_t)row * VTOK;
    __shared__ float rb[4];
    float m = -3.0e38f;
    for (int i = tid * 4; i < VTOK; i += 1024) {
        float4 v = *(const float4*)(p + i);
        m = fmaxf(m, fmaxf(fmaxf(v.x, v.y), fmaxf(v.z, v.w)));
    }
    for (int o = 32; o >= 1; o >>= 1) m = fmaxf(m, __shfl_xor(m, o));
    if ((tid & 63) == 0) rb[tid >> 6] = m;
    __syncthreads();
    m = fmaxf(fmaxf(rb[0], rb[1]), fmaxf(rb[2], rb[3]));
    float s = 0.f;
    for (int i = tid * 4; i < VTOK; i += 1024) {
        float4 v = *(const float4*)(p + i);
        s += fexp2((v.x - m) * 1.442695040888963f) + fexp2((v.y - m) * 1.442695040888963f)
           + fexp2((v.z - m) * 1.442695040888963f) + fexp2((v.w - m) * 1.442695040888963f);
    }
    for (int o = 32; o >= 1; o >>= 1) s += __shfl_xor(s, o);
    __syncthreads();
    if ((tid & 63) == 0) rb[tid >> 6] = s;
    __syncthreads();
    s = rb[0] + rb[1] + rb[2] + rb[3];
    const float lse = m + __builtin_amdgcn_logf(s) * 0.6931471805599453f;
    for (int i = tid * 4; i < VTOK; i += 1024) {
        float4 v = *(const float4*)(p + i);
        v.x -= lse; v.y -= lse; v.z -= lse; v.w -= lse;
        *(float4*)(p + i) = v;
    }
}

// ---------------- host launcher ----------------
extern "C" void kernel_launch(void* const* d_in, const int* in_sizes, int n_in,
                              void* d_out, int out_size, void* d_ws, size_t ws_size,
                              hipStream_t stream)
{
    (void)in_sizes; (void)n_in; (void)out_size; (void)ws_size;
    const int*   src       = (const int*)  d_in[0];
    const int*   tgt       = (const int*)  d_in[1];
    const float* enc_embed = (const float*)d_in[2];
    const float* enc_Wx    = (const float*)d_in[3];
    const float* enc_bx    = (const float*)d_in[4];
    const float* enc_Urz   = (const float*)d_in[5];
    const float* enc_brz   = (const float*)d_in[6];
    const float* enc_Un    = (const float*)d_in[7];
    const float* enc_bn    = (const float*)d_in[8];
    const float* dec_embed = (const float*)d_in[9];
    const float* dec_Wx    = (const float*)d_in[10];
    const float* dec_bx    = (const float*)d_in[11];
    const float* dec_Urz   = (const float*)d_in[12];
    const float* dec_brz   = (const float*)d_in[13];
    const float* dec_Un    = (const float*)d_in[14];
    const float* dec_bn    = (const float*)d_in[15];
    const float* attn_Wh   = (const float*)d_in[16];
    const float* attn_Ws   = (const float*)d_in[17];
    const float* attn_v    = (const float*)d_in[18];
    const float* out_W     = (const float*)d_in[19];
    const float* out_b     = (const float*)d_in[20];

    // --- scratch in d_out (524,288,000 B); all dead before the final GEMM overwrites ---
    char* ob = (char*)d_out;
    float* gx_enc   = (float*)(ob + 0);              // 25165824
    float* gxe_dec  = (float*)(ob + 25165824);       // 25165824
    float* wh_enc   = (float*)(ob + 50331648);       // 8388608
    u16*   Aenc     = (u16*)(ob + 58720256);         // 4194304
    u16*   Adec     = (u16*)(ob + 62914560);         // 4194304
    u16*   enc_hs   = (u16*)(ob + 67108864);         // 4194304
    u16*   spack    = (u16*)(ob + 71303168);         // 4194304
    u16*   wh_bf    = (u16*)(ob + 75497472);         // 4194304
    u16*   encWxT   = (u16*)(ob + 79691776);         // 1572864
    u16*   decWxET  = (u16*)(ob + 81264640);         // 1572864
    u16*   WhT      = (u16*)(ob + 82837504);         // 524288
    u16*   UrzET    = (u16*)(ob + 83361792);         // 1048576
    u16*   UnET     = (u16*)(ob + 84410368);         // 524288
    u16*   UrzDT    = (u16*)(ob + 84934656);         // 1048576
    u16*   UnDT     = (u16*)(ob + 85983232);         // 524288
    u16*   WsT      = (u16*)(ob + 86507520);         // 524288
    u16*   WxCT     = (u16*)(ob + 87031808);         // 1572864
    u32*   hg       = (u32*)(ob + 88604672);         // 32768
    u32*   rhg      = (u32*)(ob + 88637440);         // 32768
    u32*   ctxg     = (u32*)(ob + 88670208);         // 32768
    u32*   zg       = (u32*)(ob + 88702976);         // 65536
    u32*   gg       = (u32*)(ob + 88768512);         // 65536
    u32*   aWsg     = (u32*)(ob + 88834048);         // 65536
    u32*   barp     = (u32*)(ob + 88899584);         // 512 (enc block @0, dec block @64)

    // --- d_ws: only what must coexist with the final GEMM's output ---
    char* wb = (char*)d_ws;
    u16* outWT = (u16*)(wb + 0);          // 65536000
    u16* hctx  = (u16*)(wb + 65536000);   // 8388608

    // prep: all weights -> bf16 [N][K]
    transpose_cvt<<<dim3(48, 16),   256, 0, stream>>>(enc_Wx,  encWxT, 512, 1536);
    transpose_cvt<<<dim3(48, 16),   256, 0, stream>>>(dec_Wx,  decWxET,512, 1536);
    transpose_cvt<<<dim3(16, 16),   256, 0, stream>>>(attn_Wh, WhT,    512, 512);
    transpose_cvt<<<dim3(1000, 32), 256, 0, stream>>>(out_W,   outWT, 1024, 32000);
    transpose_cvt<<<dim3(32, 16),   256, 0, stream>>>(enc_Urz, UrzET,  512, 1024);
    transpose_cvt<<<dim3(16, 16),   256, 0, stream>>>(enc_Un,  UnET,   512, 512);
    transpose_cvt<<<dim3(32, 16),   256, 0, stream>>>(dec_Urz, UrzDT,  512, 1024);
    transpose_cvt<<<dim3(16, 16),   256, 0, stream>>>(dec_Un,  UnDT,   512, 512);
    transpose_cvt<<<dim3(16, 16),   256, 0, stream>>>(attn_Ws, WsT,    512, 512);
    transpose_cvt<<<dim3(48, 16),   256, 0, stream>>>(dec_Wx + (size_t)512 * 1536, WxCT, 512, 1536);
    gather_emb_bf16<<<4096, 128, 0, stream>>>(src, enc_embed, Aenc);
    gather_emb_bf16<<<4096, 128, 0, stream>>>(tgt, dec_embed, Adec);

    // batched input-projection GEMMs
    gemm_bf16<<<dim3(12, 32), 256, 0, stream>>>(Aenc, encWxT,  enc_bx, gx_enc,  4096, 1536, 512);
    gemm_bf16<<<dim3(12, 32), 256, 0, stream>>>(Adec, decWxET, dec_bx, gxe_dec, 4096, 1536, 512);

    init_state<<<16, 512, 0, stream>>>(hg, barp);

    // encoder (persistent cooperative, 64 WGs)
    {
        u32* barE = barp;
        void* args[] = { (void*)&gx_enc, (void*)&UrzET, (void*)&UnET, (void*)&enc_brz,
                         (void*)&enc_bn, (void*)&hg, (void*)&rhg, (void*)&zg,
                         (void*)&enc_hs, (void*)&spack, (void*)&barE };
        hipLaunchCooperativeKernel((void*)enc_coop, dim3(64), dim3(512), args, 0, stream);
    }

    // wh_enc = enc_hs @ attn_Wh; -> bf16
    gemm_bf16<<<dim3(4, 32), 256, 0, stream>>>(enc_hs, WhT, nullptr, wh_enc, 4096, 512, 512);
    cvt_f32_bf16<<<1024, 256, 0, stream>>>(wh_enc, wh_bf);

    // decoder (persistent cooperative, 96 WGs; h carried over in hg)
    {
        u32* barD = barp + 64;
        void* args[] = { (void*)&gxe_dec, (void*)&wh_bf, (void*)&spack, (void*)&attn_v,
                         (void*)&dec_brz, (void*)&dec_bn, (void*)&UrzDT, (void*)&WsT,
                         (void*)&WxCT, (void*)&UnDT, (void*)&hg, (void*)&rhg, (void*)&ctxg,
                         (void*)&zg, (void*)&gg, (void*)&aWsg, (void*)&hctx, (void*)&barD };
        hipLaunchCooperativeKernel((void*)dec_coop, dim3(96), dim3(512), args, 0, stream);
    }

    // output projection (overwrites ALL of d_out) + in-place log_softmax
    gemm_bf16<<<dim3(250, 32), 256, 0, stream>>>(hctx, outWT, out_b, (float*)d_out, 4096, VTOK, 1024);
    log_softmax_rows<<<4096, 256, 0, stream>>>((float*)d_out);
}

// Round 7
// 6768.150 us; speedup vs baseline: 2.2586x; 1.0095x over previous
//
#include <hip/hip_runtime.h>
#include <stdint.h>

#define BATCH 32
#define SEQ   128       // S == T == 128
#define HID   512
#define VTOK  32000

typedef unsigned short u16;
typedef unsigned int   u32;
typedef unsigned long long u64;
typedef float    f32x4  __attribute__((ext_vector_type(4)));
typedef short    short8 __attribute__((ext_vector_type(8)));

__device__ __forceinline__ u16 f2bf(float f) {
    u32 u = __builtin_bit_cast(u32, f);
    return (u16)((u + 0x7FFFu + ((u >> 16) & 1u)) >> 16);
}
__device__ __forceinline__ float bf2f(u16 v) {
    u32 u = ((u32)v) << 16; return __builtin_bit_cast(float, u);
}
__device__ __forceinline__ float fexp2(float x) { return __builtin_amdgcn_exp2f(x); }
__device__ __forceinline__ float frcp(float x)  { return __builtin_amdgcn_rcpf(x); }
__device__ __forceinline__ float sigmoid_f(float x) {
    return frcp(1.f + fexp2(-1.442695040888963f * x));
}
__device__ __forceinline__ float tanh_f(float x) {
    return 1.f - 2.f * frcp(1.f + fexp2(2.885390081777927f * x));
}

// ---- LLC-coherent (sc1) relaxed atomics ----
__device__ __forceinline__ u32 ld_sc1_u32(const u32* p) {
    return __hip_atomic_load(p, __ATOMIC_RELAXED, __HIP_MEMORY_SCOPE_AGENT);
}
__device__ __forceinline__ void st_sc1_u32(u32* p, u32 v) {
    __hip_atomic_store(p, v, __ATOMIC_RELAXED, __HIP_MEMORY_SCOPE_AGENT);
}
__device__ __forceinline__ u64 ld_sc1_u64(const u64* p) {
    return __hip_atomic_load(p, __ATOMIC_RELAXED, __HIP_MEMORY_SCOPE_AGENT);
}
__device__ __forceinline__ short8 ldA(const u64* base) {
    union { u64 q[2]; short8 s; } u;
    u.q[0] = ld_sc1_u64(base);
    u.q[1] = ld_sc1_u64(base + 1);
    return u.s;
}

// ---- distributed-flag grid barrier ----
// Arrival: WG w stores gen to flags[w*4] (own 16B slot) -> no RMW serialization.
// Leader (WG 0): threads 1..nwg-1 poll their flag in parallel, then release.
// Data visibility: vmcnt(0) drains this wave's (sc1) stores to LLC before arrival.
__device__ __forceinline__ void gbar(u32* flags, u32* rel, u32 gen, int nwg) {
    asm volatile("s_waitcnt vmcnt(0)" ::: "memory");
    __syncthreads();
    if (blockIdx.x == 0) {
        const int tid = threadIdx.x;
        if (tid > 0 && tid < nwg)
            while (ld_sc1_u32(flags + tid * 4) < gen) {}
        __syncthreads();
        if (tid == 0) st_sc1_u32(rel, gen);
    } else {
        if (threadIdx.x == 0) {
            st_sc1_u32(flags + (u32)blockIdx.x * 4, gen);
            while (ld_sc1_u32(rel) < gen) __builtin_amdgcn_s_sleep(1);
        }
        __syncthreads();
    }
}

// ---------------- prep kernels ----------------

// f32 [K,N] -> bf16 [N,K]
__global__ __launch_bounds__(256) void transpose_cvt(
    const float* __restrict__ src, u16* __restrict__ dst, int K, int N)
{
    __shared__ float tile[32][33];
    const int n0 = blockIdx.x * 32, k0 = blockIdx.y * 32;
    const int tx = threadIdx.x & 31, ty = threadIdx.x >> 5;
    #pragma unroll
    for (int j = 0; j < 32; j += 8)
        tile[ty + j][tx] = src[(size_t)(k0 + ty + j) * N + n0 + tx];
    __syncthreads();
    #pragma unroll
    for (int j = 0; j < 32; j += 8)
        dst[(size_t)(n0 + ty + j) * K + k0 + tx] = f2bf(tile[tx][ty + j]);
}

__global__ __launch_bounds__(256) void cvt_f32_bf16(
    const float* __restrict__ src, u16* __restrict__ dst)
{
    const size_t i = ((size_t)blockIdx.x * 256 + threadIdx.x) * 8;
    float4 v0 = *(const float4*)(src + i);
    float4 v1 = *(const float4*)(src + i + 4);
    uint4 pk;
    pk.x = (u32)f2bf(v0.x) | ((u32)f2bf(v0.y) << 16);
    pk.y = (u32)f2bf(v0.z) | ((u32)f2bf(v0.w) << 16);
    pk.z = (u32)f2bf(v1.x) | ((u32)f2bf(v1.y) << 16);
    pk.w = (u32)f2bf(v1.z) | ((u32)f2bf(v1.w) << 16);
    *(uint4*)(dst + i) = pk;
}

__global__ __launch_bounds__(128) void gather_emb_bf16(
    const int* __restrict__ idx, const float* __restrict__ emb, u16* __restrict__ out)
{
    const int r = blockIdx.x;
    const int token = idx[r];
    const int i = threadIdx.x * 4;
    float4 v = *(const float4*)(emb + (size_t)token * 512 + i);
    uint2 pk;
    pk.x = (u32)f2bf(v.x) | ((u32)f2bf(v.y) << 16);
    pk.y = (u32)f2bf(v.z) | ((u32)f2bf(v.w) << 16);
    *(uint2*)(out + (size_t)r * 512 + i) = pk;
}

// zero h (8192 u32) + barrier flag/release blocks (2048 u32)
__global__ __launch_bounds__(512) void init_state(u32* hg, u32* bar)
{
    const int i = blockIdx.x * 512 + threadIdx.x;
    hg[i] = 0u;
    if (blockIdx.x < 4) bar[blockIdx.x * 512 + threadIdx.x] = 0u;
}

// ---------------- MFMA GEMM:  C[M,N](f32) = A[M,K](bf16) * BT[N,K](bf16) + bias ----------------
__global__ __launch_bounds__(256) void gemm_bf16(
    const u16* __restrict__ A, const u16* __restrict__ BT,
    const float* __restrict__ bias, float* __restrict__ C,
    int M, int N, int K)
{
    __shared__ __align__(16) u16 As[128][40];
    __shared__ __align__(16) u16 Bs[128][40];
    const int tid  = threadIdx.x;
    const int lane = tid & 63, wave = tid >> 6;
    const int wm = (wave & 1) * 64, wn = (wave >> 1) * 64;
    const int lrow = lane & 15, lk = (lane >> 4) * 8;
    const int srow = tid >> 2, skof = (tid & 3) * 8;
    const size_t K_ = (size_t)K;
    const u16* Ag = A + ((size_t)blockIdx.y * 128 + srow) * K_ + skof;
    const u16* Bg = BT + ((size_t)blockIdx.x * 128 + srow) * K_ + skof;
    f32x4 acc[4][4] = {};
    for (int k0 = 0; k0 < K; k0 += 32) {
        uint4 a0 = *(const uint4*)(Ag + k0);
        uint4 a1 = *(const uint4*)(Ag + 64 * K_ + k0);
        uint4 b0 = *(const uint4*)(Bg + k0);
        uint4 b1 = *(const uint4*)(Bg + 64 * K_ + k0);
        __syncthreads();
        *(uint4*)&As[srow][skof]      = a0;
        *(uint4*)&As[srow + 64][skof] = a1;
        *(uint4*)&Bs[srow][skof]      = b0;
        *(uint4*)&Bs[srow + 64][skof] = b1;
        __syncthreads();
        short8 af[4], bf[4];
        #pragma unroll
        for (int i = 0; i < 4; ++i) af[i] = *(const short8*)&As[wm + i * 16 + lrow][lk];
        #pragma unroll
        for (int j = 0; j < 4; ++j) bf[j] = *(const short8*)&Bs[wn + j * 16 + lrow][lk];
        #pragma unroll
        for (int i = 0; i < 4; ++i)
            #pragma unroll
            for (int j = 0; j < 4; ++j)
                acc[i][j] = __builtin_amdgcn_mfma_f32_16x16x32_bf16(af[i], bf[j], acc[i][j], 0, 0, 0);
    }
    const int crow0 = blockIdx.y * 128 + wm + (lane >> 4) * 4;
    const int ccol0 = blockIdx.x * 128 + wn + (lane & 15);
    #pragma unroll
    for (int j = 0; j < 4; ++j) {
        const float bv = bias ? bias[ccol0 + j * 16] : 0.f;
        #pragma unroll
        for (int i = 0; i < 4; ++i)
            #pragma unroll
            for (int rr = 0; rr < 4; ++rr)
                C[(size_t)(crow0 + i * 16 + rr) * N + (ccol0 + j * 16)] = acc[i][j][rr] + bv;
    }
}

// ============ persistent cooperative encoder: 64 WGs, MFMA phases, sc1 comm ============
__global__ __launch_bounds__(512) void enc_coop(
    const float* __restrict__ gx, const u16* __restrict__ Urz, const u16* __restrict__ Un,
    const float* __restrict__ brz, const float* __restrict__ bn,
    u32* __restrict__ hg, u32* __restrict__ rhg, u32* __restrict__ zg,
    u16* __restrict__ enc_hs, u16* __restrict__ spack,
    u32* __restrict__ flags, u32* __restrict__ rel)
{
    const int w = blockIdx.x, tid = threadIdx.x;
    const int v = tid >> 6, lane = tid & 63;
    const int nl = lane & 15, kq = lane >> 4;
    const u64* hq = (const u64*)hg;
    const u64* rq = (const u64*)rhg;
    u32 gen = 0u;
    for (int t = 0; t < SEQ; ++t) {
        // ---- E1: h@Urz; waves 0,1 (bt) per WG; n-tile = w ----
        if (v < 2) {
            const int bt = v;
            const int n = w * 16 + nl;
            const int brow = bt * 16 + nl;
            const u16* wp = Urz + (size_t)n * 512 + kq * 8;
            f32x4 acc = {0.f, 0.f, 0.f, 0.f};
            #pragma unroll
            for (int k0 = 0; k0 < 512; k0 += 32) {
                short8 af = ldA(hq + brow * 128 + (k0 >> 2) + kq * 2);
                short8 bf = *(const short8*)(wp + k0);
                acc = __builtin_amdgcn_mfma_f32_16x16x32_bf16(af, bf, acc, 0, 0, 0);
            }
            if (n < 512) {               // r gate -> rh
                u32 pk[4];
                #pragma unroll
                for (int rr = 0; rr < 4; ++rr) {
                    const int b = bt * 16 + kq * 4 + rr;
                    const float gxr = gx[((size_t)(b * SEQ + t)) * 1536 + n];
                    const float r = sigmoid_f(gxr + acc[rr] + brz[n]);
                    u32 hv = ld_sc1_u32(hg + b * 256 + (n >> 1));
                    const float hold = bf2f((u16)((n & 1) ? (hv >> 16) : (hv & 0xFFFF)));
                    pk[rr] = (u32)f2bf(r * hold);
                }
                #pragma unroll
                for (int rr = 0; rr < 4; ++rr) {
                    u32 oth = (u32)__shfl_xor((int)pk[rr], 1);
                    if ((n & 1) == 0) {
                        const int b = bt * 16 + kq * 4 + rr;
                        st_sc1_u32(rhg + b * 256 + (n >> 1), (pk[rr] & 0xFFFF) | (oth << 16));
                    }
                }
            } else {                     // z gate
                #pragma unroll
                for (int rr = 0; rr < 4; ++rr) {
                    const int b = bt * 16 + kq * 4 + rr;
                    const float gxr = gx[((size_t)(b * SEQ + t)) * 1536 + n];
                    const float z = sigmoid_f(gxr + acc[rr] + brz[n]);
                    st_sc1_u32(zg + (n - 512) * 32 + b, __float_as_uint(z));
                }
            }
        }
        gbar(flags, rel, ++gen, 64);
        // ---- E2: (r*h)@Un, h update ----
        if (v < 2 && w < 32) {
            const int bt = v;
            const int n = w * 16 + nl;
            const int brow = bt * 16 + nl;
            const u16* wp = Un + (size_t)n * 512 + kq * 8;
            f32x4 acc = {0.f, 0.f, 0.f, 0.f};
            #pragma unroll
            for (int k0 = 0; k0 < 512; k0 += 32) {
                short8 af = ldA(rq + brow * 128 + (k0 >> 2) + kq * 2);
                short8 bf = *(const short8*)(wp + k0);
                acc = __builtin_amdgcn_mfma_f32_16x16x32_bf16(af, bf, acc, 0, 0, 0);
            }
            u32 pk[4];
            #pragma unroll
            for (int rr = 0; rr < 4; ++rr) {
                const int b = bt * 16 + kq * 4 + rr;
                const float gxr = gx[((size_t)(b * SEQ + t)) * 1536 + 1024 + n];
                const float nn = tanh_f(gxr + acc[rr] + bn[n]);
                const float z = __uint_as_float(ld_sc1_u32(zg + n * 32 + b));
                u32 hv = ld_sc1_u32(hg + b * 256 + (n >> 1));
                const float hold = bf2f((u16)((n & 1) ? (hv >> 16) : (hv & 0xFFFF)));
                const float hn = (1.f - z) * hold + z * nn;
                const u16 hb = f2bf(hn);
                pk[rr] = (u32)hb;
                enc_hs[((size_t)(b * SEQ + t)) * 512 + n] = hb;
                spack[(((size_t)b * 16 + (t >> 3)) * 512 + n) * 8 + (t & 7)] = hb;
            }
            #pragma unroll
            for (int rr = 0; rr < 4; ++rr) {
                u32 oth = (u32)__shfl_xor((int)pk[rr], 1);
                if ((n & 1) == 0) {
                    const int b = bt * 16 + kq * 4 + rr;
                    st_sc1_u32(hg + b * 256 + (n >> 1), (pk[rr] & 0xFFFF) | (oth << 16));
                }
            }
        }
        gbar(flags, rel, ++gen, 64);
    }
}

// ============ persistent cooperative decoder: 96 WGs, MFMA phases, sc1 comm ============
__global__ __launch_bounds__(512) void dec_coop(
    const float* __restrict__ gxe, const u16* __restrict__ wh_bf, const u16* __restrict__ spack,
    const float* __restrict__ attn_v, const float* __restrict__ brz, const float* __restrict__ bn,
    const u16* __restrict__ Urz, const u16* __restrict__ Ws,
    const u16* __restrict__ WxC, const u16* __restrict__ Un,
    u32* __restrict__ hg, u32* __restrict__ rhg, u32* __restrict__ ctxg,
    u32* __restrict__ zg, u32* __restrict__ gg, u32* __restrict__ aWsg,
    u16* __restrict__ hctx, u32* __restrict__ flags, u32* __restrict__ rel)
{
    const int w = blockIdx.x, tid = threadIdx.x;
    const int v = tid >> 6, lane = tid & 63;
    const int nl = lane & 15, kq = lane >> 4;
    __shared__ float hWsL[4 * 132], redE[512], attnL[128];   // hWsL stride 132: bank-spread
    __shared__ u16 ctxL[512];
    const u64* hq = (const u64*)hg;
    const u64* rq = (const u64*)rhg;
    const u64* cq = (const u64*)ctxg;
    u32 gen = 0u;
    for (int t = 0; t < SEQ; ++t) {
        f32x4 aPk = {0.f, 0.f, 0.f, 0.f};
        // ---- P1: h@[Urz | Ws] ----
        if (v < 2) {
            const int bt = v;
            const int n = w * 16 + nl;
            const int brow = bt * 16 + nl;
            const u16* wp = (n < 1024 ? Urz + (size_t)n * 512
                                      : Ws + (size_t)(n - 1024) * 512) + kq * 8;
            f32x4 acc = {0.f, 0.f, 0.f, 0.f};
            #pragma unroll
            for (int k0 = 0; k0 < 512; k0 += 32) {
                short8 af = ldA(hq + brow * 128 + (k0 >> 2) + kq * 2);
                short8 bf = *(const short8*)(wp + k0);
                acc = __builtin_amdgcn_mfma_f32_16x16x32_bf16(af, bf, acc, 0, 0, 0);
            }
            if (n < 1024) {
                aPk = acc;               // persists in regs to P3
            } else {
                #pragma unroll
                for (int rr = 0; rr < 4; ++rr) {
                    const int b = bt * 16 + kq * 4 + rr;
                    st_sc1_u32(aWsg + (n - 1024) * 32 + b, __float_as_uint(acc[rr]));
                }
            }
        }
        gbar(flags, rel, ++gen, 96);
        // ---- P2: attention, WG b = w < 32 ----
        if (w < 32) {
            const int b = w;
            hWsL[(tid >> 7) * 132 + (tid & 127)] = __uint_as_float(ld_sc1_u32(aWsg + tid * 32 + b));
            __syncthreads();
            {
                const int s = tid >> 2, q = tid & 3;
                const u16* whr = wh_bf + ((size_t)(b * SEQ + s)) * 512 + q * 128;
                const float* avq = attn_v + q * 128;
                const float* hwq = &hWsL[q * 132];
                float e = 0.f;
                #pragma unroll 4
                for (int i = 0; i < 128; i += 8) {
                    uint4 wv = *(const uint4*)(whr + i);
                    float4 h0 = *(const float4*)(hwq + i);
                    float4 h1 = *(const float4*)(hwq + i + 4);
                    float4 v0 = *(const float4*)(avq + i);
                    float4 v1 = *(const float4*)(avq + i + 4);
                    e += v0.x * tanh_f(bf2f((u16)(wv.x & 0xFFFF)) + h0.x)
                       + v0.y * tanh_f(bf2f((u16)(wv.x >> 16))    + h0.y)
                       + v0.z * tanh_f(bf2f((u16)(wv.y & 0xFFFF)) + h0.z)
                       + v0.w * tanh_f(bf2f((u16)(wv.y >> 16))    + h0.w)
                       + v1.x * tanh_f(bf2f((u16)(wv.z & 0xFFFF)) + h1.x)
                       + v1.y * tanh_f(bf2f((u16)(wv.z >> 16))    + h1.y)
                       + v1.z * tanh_f(bf2f((u16)(wv.w & 0xFFFF)) + h1.z)
                       + v1.w * tanh_f(bf2f((u16)(wv.w >> 16))    + h1.w);
                }
                redE[tid] = e;
            }
            __syncthreads();
            if (tid < 64) {
                float e0 = redE[4 * tid] + redE[4 * tid + 1] + redE[4 * tid + 2] + redE[4 * tid + 3];
                float e1 = redE[4 * (tid + 64)] + redE[4 * (tid + 64) + 1]
                         + redE[4 * (tid + 64) + 2] + redE[4 * (tid + 64) + 3];
                float m = fmaxf(e0, e1);
                for (int o = 32; o >= 1; o >>= 1) m = fmaxf(m, __shfl_xor(m, o));
                float p0 = fexp2((e0 - m) * 1.442695040888963f);
                float p1 = fexp2((e1 - m) * 1.442695040888963f);
                float ss = p0 + p1;
                for (int o = 32; o >= 1; o >>= 1) ss += __shfl_xor(ss, o);
                const float inv = frcp(ss);
                attnL[tid]      = p0 * inv;
                attnL[tid + 64] = p1 * inv;
            }
            __syncthreads();
            {
                const int d = tid;
                float cv = 0.f;
                const u16* sp = spack + ((size_t)b * 16 * 512 + d) * 8;
                #pragma unroll 4
                for (int sb = 0; sb < 16; ++sb) {
                    uint4 sv = *(const uint4*)(sp + (size_t)sb * 4096);
                    const float* al = &attnL[sb * 8];
                    cv += al[0] * bf2f((u16)(sv.x & 0xFFFF)) + al[1] * bf2f((u16)(sv.x >> 16))
                        + al[2] * bf2f((u16)(sv.y & 0xFFFF)) + al[3] * bf2f((u16)(sv.y >> 16))
                        + al[4] * bf2f((u16)(sv.z & 0xFFFF)) + al[5] * bf2f((u16)(sv.z >> 16))
                        + al[6] * bf2f((u16)(sv.w & 0xFFFF)) + al[7] * bf2f((u16)(sv.w >> 16));
                }
                const u16 cb = f2bf(cv);
                ctxL[d] = cb;
                hctx[((size_t)(b * SEQ + t)) * 1024 + 512 + d] = cb;
            }
            __syncthreads();
            if (tid < 256) {
                u32 pk = (u32)ctxL[2 * tid] | ((u32)ctxL[2 * tid + 1] << 16);
                st_sc1_u32(ctxg + b * 256 + tid, pk);
            }
        }
        gbar(flags, rel, ++gen, 96);
        // ---- P3: ctx@WxC + gates (aPk from P1) ----
        if (v < 2) {
            const int bt = v;
            const int n = w * 16 + nl;
            const int brow = bt * 16 + nl;
            const u16* wp = WxC + (size_t)n * 512 + kq * 8;
            f32x4 acc = {0.f, 0.f, 0.f, 0.f};
            #pragma unroll
            for (int k0 = 0; k0 < 512; k0 += 32) {
                short8 af = ldA(cq + brow * 128 + (k0 >> 2) + kq * 2);
                short8 bf = *(const short8*)(wp + k0);
                acc = __builtin_amdgcn_mfma_f32_16x16x32_bf16(af, bf, acc, 0, 0, 0);
            }
            if (n < 512) {               // r gate -> rh
                u32 pk[4];
                #pragma unroll
                for (int rr = 0; rr < 4; ++rr) {
                    const int b = bt * 16 + kq * 4 + rr;
                    const float gxr = gxe[((size_t)(b * SEQ + t)) * 1536 + n];
                    const float r = sigmoid_f(gxr + acc[rr] + aPk[rr] + brz[n]);
                    u32 hv = ld_sc1_u32(hg + b * 256 + (n >> 1));
                    const float hold = bf2f((u16)((n & 1) ? (hv >> 16) : (hv & 0xFFFF)));
                    pk[rr] = (u32)f2bf(r * hold);
                }
                #pragma unroll
                for (int rr = 0; rr < 4; ++rr) {
                    u32 oth = (u32)__shfl_xor((int)pk[rr], 1);
                    if ((n & 1) == 0) {
                        const int b = bt * 16 + kq * 4 + rr;
                        st_sc1_u32(rhg + b * 256 + (n >> 1), (pk[rr] & 0xFFFF) | (oth << 16));
                    }
                }
            } else if (n < 1024) {       // z gate
                #pragma unroll
                for (int rr = 0; rr < 4; ++rr) {
                    const int b = bt * 16 + kq * 4 + rr;
                    const float gxr = gxe[((size_t)(b * SEQ + t)) * 1536 + n];
                    const float z = sigmoid_f(gxr + acc[rr] + aPk[rr] + brz[n]);
                    st_sc1_u32(zg + (n - 512) * 32 + b, __float_as_uint(z));
                }
            } else {                     // n-gate pre-activation
                #pragma unroll
                for (int rr = 0; rr < 4; ++rr) {
                    const int b = bt * 16 + kq * 4 + rr;
                    const float gxr = gxe[((size_t)(b * SEQ + t)) * 1536 + n];
                    st_sc1_u32(gg + (n - 1024) * 32 + b, __float_as_uint(gxr + acc[rr]));
                }
            }
        }
        gbar(flags, rel, ++gen, 96);
        // ---- P4: (r*h)@Un, h update ----
        if (v < 2 && w < 32) {
            const int bt = v;
            const int n = w * 16 + nl;
            const int brow = bt * 16 + nl;
            const u16* wp = Un + (size_t)n * 512 + kq * 8;
            f32x4 acc = {0.f, 0.f, 0.f, 0.f};
            #pragma unroll
            for (int k0 = 0; k0 < 512; k0 += 32) {
                short8 af = ldA(rq + brow * 128 + (k0 >> 2) + kq * 2);
                short8 bf = *(const short8*)(wp + k0);
                acc = __builtin_amdgcn_mfma_f32_16x16x32_bf16(af, bf, acc, 0, 0, 0);
            }
            u32 pk[4];
            #pragma unroll
            for (int rr = 0; rr < 4; ++rr) {
                const int b = bt * 16 + kq * 4 + rr;
                const float gnv = __uint_as_float(ld_sc1_u32(gg + n * 32 + b));
                const float nn = tanh_f(gnv + acc[rr] + bn[n]);
                const float z = __uint_as_float(ld_sc1_u32(zg + n * 32 + b));
                u32 hv = ld_sc1_u32(hg + b * 256 + (n >> 1));
                const float hold = bf2f((u16)((n & 1) ? (hv >> 16) : (hv & 0xFFFF)));
                const float hn = (1.f - z) * hold + z * nn;
                const u16 hb = f2bf(hn);
                pk[rr] = (u32)hb;
                hctx[((size_t)(b * SEQ + t)) * 1024 + n] = hb;
            }
            #pragma unroll
            for (int rr = 0; rr < 4; ++rr) {
                u32 oth = (u32)__shfl_xor((int)pk[rr], 1);
                if ((n & 1) == 0) {
                    const int b = bt * 16 + kq * 4 + rr;
                    st_sc1_u32(hg + b * 256 + (n >> 1), (pk[rr] & 0xFFFF) | (oth << 16));
                }
            }
        }
        gbar(flags, rel, ++gen, 96);
    }
}

// ---------------- log_softmax: 2-pass (online max+sum), in-place on [4096, 32000] ----------------
__global__ __launch_bounds__(256) void log_softmax_rows(float* __restrict__ out)
{
    const int row = blockIdx.x, tid = threadIdx.x;
    float* p = out + (size_t)row * VTOK;
    __shared__ float rbM[4], rbS[4];
    const float L2E = 1.442695040888963f;
    float m = -3.0e38f, s = 0.f;
    for (int i = tid * 4; i < VTOK; i += 1024) {
        float4 v = *(const float4*)(p + i);
        float lm = fmaxf(fmaxf(v.x, v.y), fmaxf(v.z, v.w));
        float nm = fmaxf(m, lm);
        s = s * fexp2((m - nm) * L2E)
          + fexp2((v.x - nm) * L2E) + fexp2((v.y - nm) * L2E)
          + fexp2((v.z - nm) * L2E) + fexp2((v.w - nm) * L2E);
        m = nm;
    }
    for (int o = 32; o >= 1; o >>= 1) {
        float om = __shfl_xor(m, o), os = __shfl_xor(s, o);
        float nm = fmaxf(m, om);
        s = s * fexp2((m - nm) * L2E) + os * fexp2((om - nm) * L2E);
        m = nm;
    }
    if ((tid & 63) == 0) { rbM[tid >> 6] = m; rbS[tid >> 6] = s; }
    __syncthreads();
    {
        float fm = fmaxf(fmaxf(rbM[0], rbM[1]), fmaxf(rbM[2], rbM[3]));
        float fs = rbS[0] * fexp2((rbM[0] - fm) * L2E) + rbS[1] * fexp2((rbM[1] - fm) * L2E)
                 + rbS[2] * fexp2((rbM[2] - fm) * L2E) + rbS[3] * fexp2((rbM[3] - fm) * L2E);
        m = fm; s = fs;
    }
    const float lse = m + __builtin_amdgcn_logf(s) * 0.6931471805599453f;
    for (int i = tid * 4; i < VTOK; i += 1024) {
        float4 v = *(const float4*)(p + i);
        v.x -= lse; v.y -= lse; v.z -= lse; v.w -= lse;
        *(float4*)(p + i) = v;
    }
}

// ---------------- host launcher ----------------
extern "C" void kernel_launch(void* const* d_in, const int* in_sizes, int n_in,
                              void* d_out, int out_size, void* d_ws, size_t ws_size,
                              hipStream_t stream)
{
    (void)in_sizes; (void)n_in; (void)out_size; (void)ws_size;
    const int*   src       = (const int*)  d_in[0];
    const int*   tgt       = (const int*)  d_in[1];
    const float* enc_embed = (const float*)d_in[2];
    const float* enc_Wx    = (const float*)d_in[3];
    const float* enc_bx    = (const float*)d_in[4];
    const float* enc_Urz   = (const float*)d_in[5];
    const float* enc_brz   = (const float*)d_in[6];
    const float* enc_Un    = (const float*)d_in[7];
    const float* enc_bn    = (const float*)d_in[8];
    const float* dec_embed = (const float*)d_in[9];
    const float* dec_Wx    = (const float*)d_in[10];
    const float* dec_bx    = (const float*)d_in[11];
    const float* dec_Urz   = (const float*)d_in[12];
    const float* dec_brz   = (const float*)d_in[13];
    const float* dec_Un    = (const float*)d_in[14];
    const float* dec_bn    = (const float*)d_in[15];
    const float* attn_Wh   = (const float*)d_in[16];
    const float* attn_Ws   = (const float*)d_in[17];
    const float* attn_v    = (const float*)d_in[18];
    const float* out_W     = (const float*)d_in[19];
    const float* out_b     = (const float*)d_in[20];

    // --- scratch in d_out (524,288,000 B); all dead before the final GEMM overwrites ---
    char* ob = (char*)d_out;
    float* gx_enc   = (float*)(ob + 0);              // 25165824
    float* gxe_dec  = (float*)(ob + 25165824);       // 25165824
    float* wh_enc   = (float*)(ob + 50331648);       // 8388608
    u16*   Aenc     = (u16*)(ob + 58720256);         // 4194304
    u16*   Adec     = (u16*)(ob + 62914560);         // 4194304
    u16*   enc_hs   = (u16*)(ob + 67108864);         // 4194304
    u16*   spack    = (u16*)(ob + 71303168);         // 4194304
    u16*   wh_bf    = (u16*)(ob + 75497472);         // 4194304
    u16*   encWxT   = (u16*)(ob + 79691776);         // 1572864
    u16*   decWxET  = (u16*)(ob + 81264640);         // 1572864
    u16*   WhT      = (u16*)(ob + 82837504);         // 524288
    u16*   UrzET    = (u16*)(ob + 83361792);         // 1048576
    u16*   UnET     = (u16*)(ob + 84410368);         // 524288
    u16*   UrzDT    = (u16*)(ob + 84934656);         // 1048576
    u16*   UnDT     = (u16*)(ob + 85983232);         // 524288
    u16*   WsT      = (u16*)(ob + 86507520);         // 524288
    u16*   WxCT     = (u16*)(ob + 87031808);         // 1572864
    u32*   hg       = (u32*)(ob + 88604672);         // 32768
    u32*   rhg      = (u32*)(ob + 88637440);         // 32768
    u32*   ctxg     = (u32*)(ob + 88670208);         // 32768
    u32*   zg       = (u32*)(ob + 88702976);         // 65536
    u32*   gg       = (u32*)(ob + 88768512);         // 65536
    u32*   aWsg     = (u32*)(ob + 88834048);         // 65536
    u32*   barp     = (u32*)(ob + 88899584);         // 8192: encF@0, encRel@512w, decF@1024w, decRel@1536w

    // --- d_ws: only what must coexist with the final GEMM's output ---
    char* wb = (char*)d_ws;
    u16* outWT = (u16*)(wb + 0);          // 65536000
    u16* hctx  = (u16*)(wb + 65536000);   // 8388608

    // prep: all weights -> bf16 [N][K]
    transpose_cvt<<<dim3(48, 16),   256, 0, stream>>>(enc_Wx,  encWxT, 512, 1536);
    transpose_cvt<<<dim3(48, 16),   256, 0, stream>>>(dec_Wx,  decWxET,512, 1536);
    transpose_cvt<<<dim3(16, 16),   256, 0, stream>>>(attn_Wh, WhT,    512, 512);
    transpose_cvt<<<dim3(1000, 32), 256, 0, stream>>>(out_W,   outWT, 1024, 32000);
    transpose_cvt<<<dim3(32, 16),   256, 0, stream>>>(enc_Urz, UrzET,  512, 1024);
    transpose_cvt<<<dim3(16, 16),   256, 0, stream>>>(enc_Un,  UnET,   512, 512);
    transpose_cvt<<<dim3(32, 16),   256, 0, stream>>>(dec_Urz, UrzDT,  512, 1024);
    transpose_cvt<<<dim3(16, 16),   256, 0, stream>>>(dec_Un,  UnDT,   512, 512);
    transpose_cvt<<<dim3(16, 16),   256, 0, stream>>>(attn_Ws, WsT,    512, 512);
    transpose_cvt<<<dim3(48, 16),   256, 0, stream>>>(dec_Wx + (size_t)512 * 1536, WxCT, 512, 1536);
    gather_emb_bf16<<<4096, 128, 0, stream>>>(src, enc_embed, Aenc);
    gather_emb_bf16<<<4096, 128, 0, stream>>>(tgt, dec_embed, Adec);

    // batched input-projection GEMMs
    gemm_bf16<<<dim3(12, 32), 256, 0, stream>>>(Aenc, encWxT,  enc_bx, gx_enc,  4096, 1536, 512);
    gemm_bf16<<<dim3(12, 32), 256, 0, stream>>>(Adec, decWxET, dec_bx, gxe_dec, 4096, 1536, 512);

    init_state<<<16, 512, 0, stream>>>(hg, barp);

    // encoder (persistent cooperative, 64 WGs)
    {
        u32* encF = barp;          u32* encR = barp + 512;
        void* args[] = { (void*)&gx_enc, (void*)&UrzET, (void*)&UnET, (void*)&enc_brz,
                         (void*)&enc_bn, (void*)&hg, (void*)&rhg, (void*)&zg,
                         (void*)&enc_hs, (void*)&spack, (void*)&encF, (void*)&encR };
        hipLaunchCooperativeKernel((void*)enc_coop, dim3(64), dim3(512), args, 0, stream);
    }

    // wh_enc = enc_hs @ attn_Wh; -> bf16
    gemm_bf16<<<dim3(4, 32), 256, 0, stream>>>(enc_hs, WhT, nullptr, wh_enc, 4096, 512, 512);
    cvt_f32_bf16<<<1024, 256, 0, stream>>>(wh_enc, wh_bf);

    // decoder (persistent cooperative, 96 WGs; h carried over in hg)
    {
        u32* decF = barp + 1024;   u32* decR = barp + 1536;
        void* args[] = { (void*)&gxe_dec, (void*)&wh_bf, (void*)&spack, (void*)&attn_v,
                         (void*)&dec_brz, (void*)&dec_bn, (void*)&UrzDT, (void*)&WsT,
                         (void*)&WxCT, (void*)&UnDT, (void*)&hg, (void*)&rhg, (void*)&ctxg,
                         (void*)&zg, (void*)&gg, (void*)&aWsg, (void*)&hctx,
                         (void*)&decF, (void*)&decR };
        hipLaunchCooperativeKernel((void*)dec_coop, dim3(96), dim3(512), args, 0, stream);
    }

    // output projection (overwrites ALL of d_out) + in-place log_softmax
    gemm_bf16<<<dim3(250, 32), 256, 0, stream>>>(hctx, outWT, out_b, (float*)d_out, 4096, VTOK, 1024);
    log_softmax_rows<<<4096, 256, 0, stream>>>((float*)d_out);
}

// Round 8
// 6429.350 us; speedup vs baseline: 2.3776x; 1.0527x over previous
//
#include <hip/hip_runtime.h>
#include <stdint.h>

#define BATCH 32
#define SEQ   128       // S == T == 128
#define HID   512
#define VTOK  32000

typedef unsigned short u16;
typedef unsigned int   u32;
typedef unsigned long long u64;
typedef float    f32x4  __attribute__((ext_vector_type(4)));
typedef short    short8 __attribute__((ext_vector_type(8)));

__device__ __forceinline__ u16 f2bf(float f) {
    u32 u = __builtin_bit_cast(u32, f);
    return (u16)((u + 0x7FFFu + ((u >> 16) & 1u)) >> 16);
}
__device__ __forceinline__ float bf2f(u16 v) {
    u32 u = ((u32)v) << 16; return __builtin_bit_cast(float, u);
}
__device__ __forceinline__ float fexp2(float x) { return __builtin_amdgcn_exp2f(x); }
__device__ __forceinline__ float frcp(float x)  { return __builtin_amdgcn_rcpf(x); }
__device__ __forceinline__ float sigmoid_f(float x) {
    return frcp(1.f + fexp2(-1.442695040888963f * x));
}
__device__ __forceinline__ float tanh_f(float x) {
    return 1.f - 2.f * frcp(1.f + fexp2(2.885390081777927f * x));
}

// ---- LLC-coherent (sc1) relaxed atomics ----
__device__ __forceinline__ u32 ld_sc1_u32(const u32* p) {
    return __hip_atomic_load(p, __ATOMIC_RELAXED, __HIP_MEMORY_SCOPE_AGENT);
}
__device__ __forceinline__ void st_sc1_u32(u32* p, u32 v) {
    __hip_atomic_store(p, v, __ATOMIC_RELAXED, __HIP_MEMORY_SCOPE_AGENT);
}
__device__ __forceinline__ u64 ld_sc1_u64(const u64* p) {
    return __hip_atomic_load(p, __ATOMIC_RELAXED, __HIP_MEMORY_SCOPE_AGENT);
}
__device__ __forceinline__ short8 ldA(const u64* base) {
    union { u64 q[2]; short8 s; } u;
    u.q[0] = ld_sc1_u64(base);
    u.q[1] = ld_sc1_u64(base + 1);
    return u.s;
}

// ---- symmetric all-report/all-poll grid barrier: ONE LLC round-trip ----
// WG w stores gen to flags[w*16] (own 64B slot). Threads 0..nwg-1 each poll one
// flag (a wave's 64 lanes poll 64 distinct flags -> one gather per iteration).
// Monotonic gens: no reset race. Data visibility: per-wave vmcnt(0) drain
// before __syncthreads ensures all this WG's (sc1) stores are at LLC before
// the flag store (proven scheme, absmax 0.0).
__device__ __forceinline__ void gbar(u32* flags, u32 gen, int nwg) {
    asm volatile("s_waitcnt vmcnt(0)" ::: "memory");
    __syncthreads();
    if (threadIdx.x == 0) st_sc1_u32(flags + (u32)blockIdx.x * 16, gen);
    const int i = threadIdx.x;
    if (i < nwg && i != (int)blockIdx.x) {
        while (ld_sc1_u32(flags + i * 16) < gen) {}
    }
    __syncthreads();
}

// ---------------- prep kernels ----------------

// f32 [K,N] -> bf16 [N,K]
__global__ __launch_bounds__(256) void transpose_cvt(
    const float* __restrict__ src, u16* __restrict__ dst, int K, int N)
{
    __shared__ float tile[32][33];
    const int n0 = blockIdx.x * 32, k0 = blockIdx.y * 32;
    const int tx = threadIdx.x & 31, ty = threadIdx.x >> 5;
    #pragma unroll
    for (int j = 0; j < 32; j += 8)
        tile[ty + j][tx] = src[(size_t)(k0 + ty + j) * N + n0 + tx];
    __syncthreads();
    #pragma unroll
    for (int j = 0; j < 32; j += 8)
        dst[(size_t)(n0 + ty + j) * K + k0 + tx] = f2bf(tile[tx][ty + j]);
}

__global__ __launch_bounds__(256) void cvt_f32_bf16(
    const float* __restrict__ src, u16* __restrict__ dst)
{
    const size_t i = ((size_t)blockIdx.x * 256 + threadIdx.x) * 8;
    float4 v0 = *(const float4*)(src + i);
    float4 v1 = *(const float4*)(src + i + 4);
    uint4 pk;
    pk.x = (u32)f2bf(v0.x) | ((u32)f2bf(v0.y) << 16);
    pk.y = (u32)f2bf(v0.z) | ((u32)f2bf(v0.w) << 16);
    pk.z = (u32)f2bf(v1.x) | ((u32)f2bf(v1.y) << 16);
    pk.w = (u32)f2bf(v1.z) | ((u32)f2bf(v1.w) << 16);
    *(uint4*)(dst + i) = pk;
}

__global__ __launch_bounds__(128) void gather_emb_bf16(
    const int* __restrict__ idx, const float* __restrict__ emb, u16* __restrict__ out)
{
    const int r = blockIdx.x;
    const int token = idx[r];
    const int i = threadIdx.x * 4;
    float4 v = *(const float4*)(emb + (size_t)token * 512 + i);
    uint2 pk;
    pk.x = (u32)f2bf(v.x) | ((u32)f2bf(v.y) << 16);
    pk.y = (u32)f2bf(v.z) | ((u32)f2bf(v.w) << 16);
    *(uint2*)(out + (size_t)r * 512 + i) = pk;
}

// zero h (8192 u32) + barrier flag blocks
__global__ __launch_bounds__(512) void init_state(u32* hg, u32* bar)
{
    const int i = blockIdx.x * 512 + threadIdx.x;
    hg[i] = 0u;
    if (blockIdx.x < 8) bar[blockIdx.x * 512 + threadIdx.x] = 0u;
}

// ---------------- MFMA GEMM:  C[M,N](f32) = A[M,K](bf16) * BT[N,K](bf16) + bias ----------------
__global__ __launch_bounds__(256) void gemm_bf16(
    const u16* __restrict__ A, const u16* __restrict__ BT,
    const float* __restrict__ bias, float* __restrict__ C,
    int M, int N, int K)
{
    __shared__ __align__(16) u16 As[128][40];
    __shared__ __align__(16) u16 Bs[128][40];
    const int tid  = threadIdx.x;
    const int lane = tid & 63, wave = tid >> 6;
    const int wm = (wave & 1) * 64, wn = (wave >> 1) * 64;
    const int lrow = lane & 15, lk = (lane >> 4) * 8;
    const int srow = tid >> 2, skof = (tid & 3) * 8;
    const size_t K_ = (size_t)K;
    const u16* Ag = A + ((size_t)blockIdx.y * 128 + srow) * K_ + skof;
    const u16* Bg = BT + ((size_t)blockIdx.x * 128 + srow) * K_ + skof;
    f32x4 acc[4][4] = {};
    for (int k0 = 0; k0 < K; k0 += 32) {
        uint4 a0 = *(const uint4*)(Ag + k0);
        uint4 a1 = *(const uint4*)(Ag + 64 * K_ + k0);
        uint4 b0 = *(const uint4*)(Bg + k0);
        uint4 b1 = *(const uint4*)(Bg + 64 * K_ + k0);
        __syncthreads();
        *(uint4*)&As[srow][skof]      = a0;
        *(uint4*)&As[srow + 64][skof] = a1;
        *(uint4*)&Bs[srow][skof]      = b0;
        *(uint4*)&Bs[srow + 64][skof] = b1;
        __syncthreads();
        short8 af[4], bf[4];
        #pragma unroll
        for (int i = 0; i < 4; ++i) af[i] = *(const short8*)&As[wm + i * 16 + lrow][lk];
        #pragma unroll
        for (int j = 0; j < 4; ++j) bf[j] = *(const short8*)&Bs[wn + j * 16 + lrow][lk];
        #pragma unroll
        for (int i = 0; i < 4; ++i)
            #pragma unroll
            for (int j = 0; j < 4; ++j)
                acc[i][j] = __builtin_amdgcn_mfma_f32_16x16x32_bf16(af[i], bf[j], acc[i][j], 0, 0, 0);
    }
    const int crow0 = blockIdx.y * 128 + wm + (lane >> 4) * 4;
    const int ccol0 = blockIdx.x * 128 + wn + (lane & 15);
    #pragma unroll
    for (int j = 0; j < 4; ++j) {
        const float bv = bias ? bias[ccol0 + j * 16] : 0.f;
        #pragma unroll
        for (int i = 0; i < 4; ++i)
            #pragma unroll
            for (int rr = 0; rr < 4; ++rr)
                C[(size_t)(crow0 + i * 16 + rr) * N + (ccol0 + j * 16)] = acc[i][j][rr] + bv;
    }
}

// ============ persistent cooperative encoder: 64 WGs, MFMA phases, sc1 comm ============
__global__ __launch_bounds__(512) void enc_coop(
    const float* __restrict__ gx, const u16* __restrict__ Urz, const u16* __restrict__ Un,
    const float* __restrict__ brz, const float* __restrict__ bn,
    u32* __restrict__ hg, u32* __restrict__ rhg, u32* __restrict__ zg,
    u16* __restrict__ enc_hs, u16* __restrict__ spack,
    u32* __restrict__ flags)
{
    const int w = blockIdx.x, tid = threadIdx.x;
    const int v = tid >> 6, lane = tid & 63;
    const int nl = lane & 15, kq = lane >> 4;
    const u64* hq = (const u64*)hg;
    const u64* rq = (const u64*)rhg;
    u32 gen = 0u;
    for (int t = 0; t < SEQ; ++t) {
        // ---- E1: h@Urz; waves 0,1 (bt) per WG; n-tile = w ----
        if (v < 2) {
            const int bt = v;
            const int n = w * 16 + nl;
            const int brow = bt * 16 + nl;
            // prefetch gate inputs (independent of MFMA) so latency hides under MFMA
            float gxr_pf[4]; u32 hv_pf[4];
            #pragma unroll
            for (int rr = 0; rr < 4; ++rr) {
                const int b = bt * 16 + kq * 4 + rr;
                gxr_pf[rr] = gx[((size_t)(b * SEQ + t)) * 1536 + n];
                if (n < 512) hv_pf[rr] = ld_sc1_u32(hg + b * 256 + (n >> 1));
            }
            const u16* wp = Urz + (size_t)n * 512 + kq * 8;
            f32x4 acc = {0.f, 0.f, 0.f, 0.f};
            #pragma unroll
            for (int k0 = 0; k0 < 512; k0 += 32) {
                short8 af = ldA(hq + brow * 128 + (k0 >> 2) + kq * 2);
                short8 bf = *(const short8*)(wp + k0);
                acc = __builtin_amdgcn_mfma_f32_16x16x32_bf16(af, bf, acc, 0, 0, 0);
            }
            if (n < 512) {               // r gate -> rh
                u32 pk[4];
                #pragma unroll
                for (int rr = 0; rr < 4; ++rr) {
                    const float r = sigmoid_f(gxr_pf[rr] + acc[rr] + brz[n]);
                    const float hold = bf2f((u16)((n & 1) ? (hv_pf[rr] >> 16) : (hv_pf[rr] & 0xFFFF)));
                    pk[rr] = (u32)f2bf(r * hold);
                }
                #pragma unroll
                for (int rr = 0; rr < 4; ++rr) {
                    u32 oth = (u32)__shfl_xor((int)pk[rr], 1);
                    if ((n & 1) == 0) {
                        const int b = bt * 16 + kq * 4 + rr;
                        st_sc1_u32(rhg + b * 256 + (n >> 1), (pk[rr] & 0xFFFF) | (oth << 16));
                    }
                }
            } else {                     // z gate
                #pragma unroll
                for (int rr = 0; rr < 4; ++rr) {
                    const int b = bt * 16 + kq * 4 + rr;
                    const float z = sigmoid_f(gxr_pf[rr] + acc[rr] + brz[n]);
                    st_sc1_u32(zg + (n - 512) * 32 + b, __float_as_uint(z));
                }
            }
        }
        gbar(flags, ++gen, 64);
        // ---- E2: (r*h)@Un, h update ----
        if (v < 2 && w < 32) {
            const int bt = v;
            const int n = w * 16 + nl;
            const int brow = bt * 16 + nl;
            float gxr_pf[4]; u32 hv_pf[4], zv_pf[4];
            #pragma unroll
            for (int rr = 0; rr < 4; ++rr) {
                const int b = bt * 16 + kq * 4 + rr;
                gxr_pf[rr] = gx[((size_t)(b * SEQ + t)) * 1536 + 1024 + n];
                hv_pf[rr] = ld_sc1_u32(hg + b * 256 + (n >> 1));
                zv_pf[rr] = ld_sc1_u32(zg + n * 32 + b);
            }
            const u16* wp = Un + (size_t)n * 512 + kq * 8;
            f32x4 acc = {0.f, 0.f, 0.f, 0.f};
            #pragma unroll
            for (int k0 = 0; k0 < 512; k0 += 32) {
                short8 af = ldA(rq + brow * 128 + (k0 >> 2) + kq * 2);
                short8 bf = *(const short8*)(wp + k0);
                acc = __builtin_amdgcn_mfma_f32_16x16x32_bf16(af, bf, acc, 0, 0, 0);
            }
            u32 pk[4];
            #pragma unroll
            for (int rr = 0; rr < 4; ++rr) {
                const int b = bt * 16 + kq * 4 + rr;
                const float nn = tanh_f(gxr_pf[rr] + acc[rr] + bn[n]);
                const float z = __uint_as_float(zv_pf[rr]);
                const float hold = bf2f((u16)((n & 1) ? (hv_pf[rr] >> 16) : (hv_pf[rr] & 0xFFFF)));
                const float hn = (1.f - z) * hold + z * nn;
                const u16 hb = f2bf(hn);
                pk[rr] = (u32)hb;
                enc_hs[((size_t)(b * SEQ + t)) * 512 + n] = hb;
                spack[(((size_t)b * 16 + (t >> 3)) * 512 + n) * 8 + (t & 7)] = hb;
            }
            #pragma unroll
            for (int rr = 0; rr < 4; ++rr) {
                u32 oth = (u32)__shfl_xor((int)pk[rr], 1);
                if ((n & 1) == 0) {
                    const int b = bt * 16 + kq * 4 + rr;
                    st_sc1_u32(hg + b * 256 + (n >> 1), (pk[rr] & 0xFFFF) | (oth << 16));
                }
            }
        }
        gbar(flags, ++gen, 64);
    }
}

// ============ persistent cooperative decoder: 96 WGs, MFMA phases, sc1 comm ============
__global__ __launch_bounds__(512) void dec_coop(
    const float* __restrict__ gxe, const u16* __restrict__ wh_bf, const u16* __restrict__ spack,
    const float* __restrict__ attn_v, const float* __restrict__ brz, const float* __restrict__ bn,
    const u16* __restrict__ Urz, const u16* __restrict__ Ws,
    const u16* __restrict__ WxC, const u16* __restrict__ Un,
    u32* __restrict__ hg, u32* __restrict__ rhg, u32* __restrict__ ctxg,
    u32* __restrict__ zg, u32* __restrict__ gg, u32* __restrict__ aWsg,
    u16* __restrict__ hctx, u32* __restrict__ flags)
{
    const int w = blockIdx.x, tid = threadIdx.x;
    const int v = tid >> 6, lane = tid & 63;
    const int nl = lane & 15, kq = lane >> 4;
    __shared__ float hWsL[4 * 132], redE[512], attnL[128];
    __shared__ u16 ctxL[512];
    const u64* hq = (const u64*)hg;
    const u64* rq = (const u64*)rhg;
    const u64* cq = (const u64*)ctxg;
    u32 gen = 0u;
    for (int t = 0; t < SEQ; ++t) {
        f32x4 aPk = {0.f, 0.f, 0.f, 0.f};
        // ---- P1: h@[Urz | Ws] ----
        if (v < 2) {
            const int bt = v;
            const int n = w * 16 + nl;
            const int brow = bt * 16 + nl;
            const u16* wp = (n < 1024 ? Urz + (size_t)n * 512
                                      : Ws + (size_t)(n - 1024) * 512) + kq * 8;
            f32x4 acc = {0.f, 0.f, 0.f, 0.f};
            #pragma unroll
            for (int k0 = 0; k0 < 512; k0 += 32) {
                short8 af = ldA(hq + brow * 128 + (k0 >> 2) + kq * 2);
                short8 bf = *(const short8*)(wp + k0);
                acc = __builtin_amdgcn_mfma_f32_16x16x32_bf16(af, bf, acc, 0, 0, 0);
            }
            if (n < 1024) {
                aPk = acc;               // persists in regs to P3
            } else {
                #pragma unroll
                for (int rr = 0; rr < 4; ++rr) {
                    const int b = bt * 16 + kq * 4 + rr;
                    st_sc1_u32(aWsg + (n - 1024) * 32 + b, __float_as_uint(acc[rr]));
                }
            }
        }
        gbar(flags, ++gen, 96);
        // ---- P2: attention, WG b = w < 32 ----
        if (w < 32) {
            const int b = w;
            hWsL[(tid >> 7) * 132 + (tid & 127)] = __uint_as_float(ld_sc1_u32(aWsg + tid * 32 + b));
            __syncthreads();
            {
                const int s = tid >> 2, q = tid & 3;
                const u16* whr = wh_bf + ((size_t)(b * SEQ + s)) * 512 + q * 128;
                const float* avq = attn_v + q * 128;
                const float* hwq = &hWsL[q * 132];
                float e = 0.f;
                #pragma unroll 4
                for (int i = 0; i < 128; i += 8) {
                    uint4 wv = *(const uint4*)(whr + i);
                    float4 h0 = *(const float4*)(hwq + i);
                    float4 h1 = *(const float4*)(hwq + i + 4);
                    float4 v0 = *(const float4*)(avq + i);
                    float4 v1 = *(const float4*)(avq + i + 4);
                    e += v0.x * tanh_f(bf2f((u16)(wv.x & 0xFFFF)) + h0.x)
                       + v0.y * tanh_f(bf2f((u16)(wv.x >> 16))    + h0.y)
                       + v0.z * tanh_f(bf2f((u16)(wv.y & 0xFFFF)) + h0.z)
                       + v0.w * tanh_f(bf2f((u16)(wv.y >> 16))    + h0.w)
                       + v1.x * tanh_f(bf2f((u16)(wv.z & 0xFFFF)) + h1.x)
                       + v1.y * tanh_f(bf2f((u16)(wv.z >> 16))    + h1.y)
                       + v1.z * tanh_f(bf2f((u16)(wv.w & 0xFFFF)) + h1.z)
                       + v1.w * tanh_f(bf2f((u16)(wv.w >> 16))    + h1.w);
                }
                redE[tid] = e;
            }
            __syncthreads();
            if (tid < 64) {
                float e0 = redE[4 * tid] + redE[4 * tid + 1] + redE[4 * tid + 2] + redE[4 * tid + 3];
                float e1 = redE[4 * (tid + 64)] + redE[4 * (tid + 64) + 1]
                         + redE[4 * (tid + 64) + 2] + redE[4 * (tid + 64) + 3];
                float m = fmaxf(e0, e1);
                for (int o = 32; o >= 1; o >>= 1) m = fmaxf(m, __shfl_xor(m, o));
                float p0 = fexp2((e0 - m) * 1.442695040888963f);
                float p1 = fexp2((e1 - m) * 1.442695040888963f);
                float ss = p0 + p1;
                for (int o = 32; o >= 1; o >>= 1) ss += __shfl_xor(ss, o);
                const float inv = frcp(ss);
                attnL[tid]      = p0 * inv;
                attnL[tid + 64] = p1 * inv;
            }
            __syncthreads();
            {
                const int d = tid;
                float cv = 0.f;
                const u16* sp = spack + ((size_t)b * 16 * 512 + d) * 8;
                #pragma unroll 4
                for (int sb = 0; sb < 16; ++sb) {
                    uint4 sv = *(const uint4*)(sp + (size_t)sb * 4096);
                    const float* al = &attnL[sb * 8];
                    cv += al[0] * bf2f((u16)(sv.x & 0xFFFF)) + al[1] * bf2f((u16)(sv.x >> 16))
                        + al[2] * bf2f((u16)(sv.y & 0xFFFF)) + al[3] * bf2f((u16)(sv.y >> 16))
                        + al[4] * bf2f((u16)(sv.z & 0xFFFF)) + al[5] * bf2f((u16)(sv.z >> 16))
                        + al[6] * bf2f((u16)(sv.w & 0xFFFF)) + al[7] * bf2f((u16)(sv.w >> 16));
                }
                const u16 cb = f2bf(cv);
                ctxL[d] = cb;
                hctx[((size_t)(b * SEQ + t)) * 1024 + 512 + d] = cb;
            }
            __syncthreads();
            if (tid < 256) {
                u32 pk = (u32)ctxL[2 * tid] | ((u32)ctxL[2 * tid + 1] << 16);
                st_sc1_u32(ctxg + b * 256 + tid, pk);
            }
        }
        gbar(flags, ++gen, 96);
        // ---- P3: ctx@WxC + gates (aPk from P1) ----
        if (v < 2) {
            const int bt = v;
            const int n = w * 16 + nl;
            const int brow = bt * 16 + nl;
            float gxr_pf[4]; u32 hv_pf[4];
            #pragma unroll
            for (int rr = 0; rr < 4; ++rr) {
                const int b = bt * 16 + kq * 4 + rr;
                gxr_pf[rr] = gxe[((size_t)(b * SEQ + t)) * 1536 + n];
                if (n < 512) hv_pf[rr] = ld_sc1_u32(hg + b * 256 + (n >> 1));
            }
            const u16* wp = WxC + (size_t)n * 512 + kq * 8;
            f32x4 acc = {0.f, 0.f, 0.f, 0.f};
            #pragma unroll
            for (int k0 = 0; k0 < 512; k0 += 32) {
                short8 af = ldA(cq + brow * 128 + (k0 >> 2) + kq * 2);
                short8 bf = *(const short8*)(wp + k0);
                acc = __builtin_amdgcn_mfma_f32_16x16x32_bf16(af, bf, acc, 0, 0, 0);
            }
            if (n < 512) {               // r gate -> rh
                u32 pk[4];
                #pragma unroll
                for (int rr = 0; rr < 4; ++rr) {
                    const float r = sigmoid_f(gxr_pf[rr] + acc[rr] + aPk[rr] + brz[n]);
                    const float hold = bf2f((u16)((n & 1) ? (hv_pf[rr] >> 16) : (hv_pf[rr] & 0xFFFF)));
                    pk[rr] = (u32)f2bf(r * hold);
                }
                #pragma unroll
                for (int rr = 0; rr < 4; ++rr) {
                    u32 oth = (u32)__shfl_xor((int)pk[rr], 1);
                    if ((n & 1) == 0) {
                        const int b = bt * 16 + kq * 4 + rr;
                        st_sc1_u32(rhg + b * 256 + (n >> 1), (pk[rr] & 0xFFFF) | (oth << 16));
                    }
                }
            } else if (n < 1024) {       // z gate
                #pragma unroll
                for (int rr = 0; rr < 4; ++rr) {
                    const int b = bt * 16 + kq * 4 + rr;
                    const float z = sigmoid_f(gxr_pf[rr] + acc[rr] + aPk[rr] + brz[n]);
                    st_sc1_u32(zg + (n - 512) * 32 + b, __float_as_uint(z));
                }
            } else {                     // n-gate pre-activation
                #pragma unroll
                for (int rr = 0; rr < 4; ++rr) {
                    const int b = bt * 16 + kq * 4 + rr;
                    st_sc1_u32(gg + (n - 1024) * 32 + b, __float_as_uint(gxr_pf[rr] + acc[rr]));
                }
            }
        }
        gbar(flags, ++gen, 96);
        // ---- P4: (r*h)@Un, h update ----
        if (v < 2 && w < 32) {
            const int bt = v;
            const int n = w * 16 + nl;
            const int brow = bt * 16 + nl;
            u32 gv_pf[4], zv_pf[4], hv_pf[4];
            #pragma unroll
            for (int rr = 0; rr < 4; ++rr) {
                const int b = bt * 16 + kq * 4 + rr;
                gv_pf[rr] = ld_sc1_u32(gg + n * 32 + b);
                zv_pf[rr] = ld_sc1_u32(zg + n * 32 + b);
                hv_pf[rr] = ld_sc1_u32(hg + b * 256 + (n >> 1));
            }
            const u16* wp = Un + (size_t)n * 512 + kq * 8;
            f32x4 acc = {0.f, 0.f, 0.f, 0.f};
            #pragma unroll
            for (int k0 = 0; k0 < 512; k0 += 32) {
                short8 af = ldA(rq + brow * 128 + (k0 >> 2) + kq * 2);
                short8 bf = *(const short8*)(wp + k0);
                acc = __builtin_amdgcn_mfma_f32_16x16x32_bf16(af, bf, acc, 0, 0, 0);
            }
            u32 pk[4];
            #pragma unroll
            for (int rr = 0; rr < 4; ++rr) {
                const int b = bt * 16 + kq * 4 + rr;
                const float nn = tanh_f(__uint_as_float(gv_pf[rr]) + acc[rr] + bn[n]);
                const float z = __uint_as_float(zv_pf[rr]);
                const float hold = bf2f((u16)((n & 1) ? (hv_pf[rr] >> 16) : (hv_pf[rr] & 0xFFFF)));
                const float hn = (1.f - z) * hold + z * nn;
                const u16 hb = f2bf(hn);
                pk[rr] = (u32)hb;
                hctx[((size_t)(b * SEQ + t)) * 1024 + n] = hb;
            }
            #pragma unroll
            for (int rr = 0; rr < 4; ++rr) {
                u32 oth = (u32)__shfl_xor((int)pk[rr], 1);
                if ((n & 1) == 0) {
                    const int b = bt * 16 + kq * 4 + rr;
                    st_sc1_u32(hg + b * 256 + (n >> 1), (pk[rr] & 0xFFFF) | (oth << 16));
                }
            }
        }
        gbar(flags, ++gen, 96);
    }
}

// ---------------- log_softmax: 2-pass (online max+sum), in-place on [4096, 32000] ----------------
__global__ __launch_bounds__(256) void log_softmax_rows(float* __restrict__ out)
{
    const int row = blockIdx.x, tid = threadIdx.x;
    float* p = out + (size_t)row * VTOK;
    __shared__ float rbM[4], rbS[4];
    const float L2E = 1.442695040888963f;
    float m = -3.0e38f, s = 0.f;
    for (int i = tid * 4; i < VTOK; i += 1024) {
        float4 v = *(const float4*)(p + i);
        float lm = fmaxf(fmaxf(v.x, v.y), fmaxf(v.z, v.w));
        float nm = fmaxf(m, lm);
        s = s * fexp2((m - nm) * L2E)
          + fexp2((v.x - nm) * L2E) + fexp2((v.y - nm) * L2E)
          + fexp2((v.z - nm) * L2E) + fexp2((v.w - nm) * L2E);
        m = nm;
    }
    for (int o = 32; o >= 1; o >>= 1) {
        float om = __shfl_xor(m, o), os = __shfl_xor(s, o);
        float nm = fmaxf(m, om);
        s = s * fexp2((m - nm) * L2E) + os * fexp2((om - nm) * L2E);
        m = nm;
    }
    if ((tid & 63) == 0) { rbM[tid >> 6] = m; rbS[tid >> 6] = s; }
    __syncthreads();
    {
        float fm = fmaxf(fmaxf(rbM[0], rbM[1]), fmaxf(rbM[2], rbM[3]));
        float fs = rbS[0] * fexp2((rbM[0] - fm) * L2E) + rbS[1] * fexp2((rbM[1] - fm) * L2E)
                 + rbS[2] * fexp2((rbM[2] - fm) * L2E) + rbS[3] * fexp2((rbM[3] - fm) * L2E);
        m = fm; s = fs;
    }
    const float lse = m + __builtin_amdgcn_logf(s) * 0.6931471805599453f;
    for (int i = tid * 4; i < VTOK; i += 1024) {
        float4 v = *(const float4*)(p + i);
        v.x -= lse; v.y -= lse; v.z -= lse; v.w -= lse;
        *(float4*)(p + i) = v;
    }
}

// ---------------- host launcher ----------------
extern "C" void kernel_launch(void* const* d_in, const int* in_sizes, int n_in,
                              void* d_out, int out_size, void* d_ws, size_t ws_size,
                              hipStream_t stream)
{
    (void)in_sizes; (void)n_in; (void)out_size; (void)ws_size;
    const int*   src       = (const int*)  d_in[0];
    const int*   tgt       = (const int*)  d_in[1];
    const float* enc_embed = (const float*)d_in[2];
    const float* enc_Wx    = (const float*)d_in[3];
    const float* enc_bx    = (const float*)d_in[4];
    const float* enc_Urz   = (const float*)d_in[5];
    const float* enc_brz   = (const float*)d_in[6];
    const float* enc_Un    = (const float*)d_in[7];
    const float* enc_bn    = (const float*)d_in[8];
    const float* dec_embed = (const float*)d_in[9];
    const float* dec_Wx    = (const float*)d_in[10];
    const float* dec_bx    = (const float*)d_in[11];
    const float* dec_Urz   = (const float*)d_in[12];
    const float* dec_brz   = (const float*)d_in[13];
    const float* dec_Un    = (const float*)d_in[14];
    const float* dec_bn    = (const float*)d_in[15];
    const float* attn_Wh   = (const float*)d_in[16];
    const float* attn_Ws   = (const float*)d_in[17];
    const float* attn_v    = (const float*)d_in[18];
    const float* out_W     = (const float*)d_in[19];
    const float* out_b     = (const float*)d_in[20];

    // --- scratch in d_out (524,288,000 B); all dead before the final GEMM overwrites ---
    char* ob = (char*)d_out;
    float* gx_enc   = (float*)(ob + 0);              // 25165824
    float* gxe_dec  = (float*)(ob + 25165824);       // 25165824
    float* wh_enc   = (float*)(ob + 50331648);       // 8388608
    u16*   Aenc     = (u16*)(ob + 58720256);         // 4194304
    u16*   Adec     = (u16*)(ob + 62914560);         // 4194304
    u16*   enc_hs   = (u16*)(ob + 67108864);         // 4194304
    u16*   spack    = (u16*)(ob + 71303168);         // 4194304
    u16*   wh_bf    = (u16*)(ob + 75497472);         // 4194304
    u16*   encWxT   = (u16*)(ob + 79691776);         // 1572864
    u16*   decWxET  = (u16*)(ob + 81264640);         // 1572864
    u16*   WhT      = (u16*)(ob + 82837504);         // 524288
    u16*   UrzET    = (u16*)(ob + 83361792);         // 1048576
    u16*   UnET     = (u16*)(ob + 84410368);         // 524288
    u16*   UrzDT    = (u16*)(ob + 84934656);         // 1048576
    u16*   UnDT     = (u16*)(ob + 85983232);         // 524288
    u16*   WsT      = (u16*)(ob + 86507520);         // 524288
    u16*   WxCT     = (u16*)(ob + 87031808);         // 1572864
    u32*   hg       = (u32*)(ob + 88604672);         // 32768
    u32*   rhg      = (u32*)(ob + 88637440);         // 32768
    u32*   ctxg     = (u32*)(ob + 88670208);         // 32768
    u32*   zg       = (u32*)(ob + 88702976);         // 65536
    u32*   gg       = (u32*)(ob + 88768512);         // 65536
    u32*   aWsg     = (u32*)(ob + 88834048);         // 65536
    u32*   barp     = (u32*)(ob + 88899584);         // 16384: encFlags@0 (64x16 u32), decFlags@+4096B (96x16 u32)

    // --- d_ws: only what must coexist with the final GEMM's output ---
    char* wb = (char*)d_ws;
    u16* outWT = (u16*)(wb + 0);          // 65536000
    u16* hctx  = (u16*)(wb + 65536000);   // 8388608

    // prep: all weights -> bf16 [N][K]
    transpose_cvt<<<dim3(48, 16),   256, 0, stream>>>(enc_Wx,  encWxT, 512, 1536);
    transpose_cvt<<<dim3(48, 16),   256, 0, stream>>>(dec_Wx,  decWxET,512, 1536);
    transpose_cvt<<<dim3(16, 16),   256, 0, stream>>>(attn_Wh, WhT,    512, 512);
    transpose_cvt<<<dim3(1000, 32), 256, 0, stream>>>(out_W,   outWT, 1024, 32000);
    transpose_cvt<<<dim3(32, 16),   256, 0, stream>>>(enc_Urz, UrzET,  512, 1024);
    transpose_cvt<<<dim3(16, 16),   256, 0, stream>>>(enc_Un,  UnET,   512, 512);
    transpose_cvt<<<dim3(32, 16),   256, 0, stream>>>(dec_Urz, UrzDT,  512, 1024);
    transpose_cvt<<<dim3(16, 16),   256, 0, stream>>>(dec_Un,  UnDT,   512, 512);
    transpose_cvt<<<dim3(16, 16),   256, 0, stream>>>(attn_Ws, WsT,    512, 512);
    transpose_cvt<<<dim3(48, 16),   256, 0, stream>>>(dec_Wx + (size_t)512 * 1536, WxCT, 512, 1536);
    gather_emb_bf16<<<4096, 128, 0, stream>>>(src, enc_embed, Aenc);
    gather_emb_bf16<<<4096, 128, 0, stream>>>(tgt, dec_embed, Adec);

    // batched input-projection GEMMs
    gemm_bf16<<<dim3(12, 32), 256, 0, stream>>>(Aenc, encWxT,  enc_bx, gx_enc,  4096, 1536, 512);
    gemm_bf16<<<dim3(12, 32), 256, 0, stream>>>(Adec, decWxET, dec_bx, gxe_dec, 4096, 1536, 512);

    init_state<<<16, 512, 0, stream>>>(hg, barp);

    // encoder (persistent cooperative, 64 WGs)
    {
        u32* encF = barp;
        void* args[] = { (void*)&gx_enc, (void*)&UrzET, (void*)&UnET, (void*)&enc_brz,
                         (void*)&enc_bn, (void*)&hg, (void*)&rhg, (void*)&zg,
                         (void*)&enc_hs, (void*)&spack, (void*)&encF };
        hipLaunchCooperativeKernel((void*)enc_coop, dim3(64), dim3(512), args, 0, stream);
    }

    // wh_enc = enc_hs @ attn_Wh; -> bf16
    gemm_bf16<<<dim3(4, 32), 256, 0, stream>>>(enc_hs, WhT, nullptr, wh_enc, 4096, 512, 512);
    cvt_f32_bf16<<<1024, 256, 0, stream>>>(wh_enc, wh_bf);

    // decoder (persistent cooperative, 96 WGs; h carried over in hg)
    {
        u32* decF = barp + 1024;
        void* args[] = { (void*)&gxe_dec, (void*)&wh_bf, (void*)&spack, (void*)&attn_v,
                         (void*)&dec_brz, (void*)&dec_bn, (void*)&UrzDT, (void*)&WsT,
                         (void*)&WxCT, (void*)&UnDT, (void*)&hg, (void*)&rhg, (void*)&ctxg,
                         (void*)&zg, (void*)&gg, (void*)&aWsg, (void*)&hctx, (void*)&decF };
        hipLaunchCooperativeKernel((void*)dec_coop, dim3(96), dim3(512), args, 0, stream);
    }

    // output projection (overwrites ALL of d_out) + in-place log_softmax
    gemm_bf16<<<dim3(250, 32), 256, 0, stream>>>(hctx, outWT, out_b, (float*)d_out, 4096, VTOK, 1024);
    log_softmax_rows<<<4096, 256, 0, stream>>>((float*)d_out);
}

// Round 9
// 6397.241 us; speedup vs baseline: 2.3896x; 1.0050x over previous
//
#include <hip/hip_runtime.h>
#include <stdint.h>

#define BATCH 32
#define SEQ   128       // S == T == 128
#define HID   512
#define VTOK  32000

typedef unsigned short u16;
typedef unsigned int   u32;
typedef unsigned long long u64;
typedef float    f32x4  __attribute__((ext_vector_type(4)));
typedef short    short8 __attribute__((ext_vector_type(8)));

__device__ __forceinline__ u16 f2bf(float f) {
    u32 u = __builtin_bit_cast(u32, f);
    return (u16)((u + 0x7FFFu + ((u >> 16) & 1u)) >> 16);
}
__device__ __forceinline__ float bf2f(u16 v) {
    u32 u = ((u32)v) << 16; return __builtin_bit_cast(float, u);
}
__device__ __forceinline__ float fexp2(float x) { return __builtin_amdgcn_exp2f(x); }
__device__ __forceinline__ float frcp(float x)  { return __builtin_amdgcn_rcpf(x); }
__device__ __forceinline__ float sigmoid_f(float x) {
    return frcp(1.f + fexp2(-1.442695040888963f * x));
}
__device__ __forceinline__ float tanh_f(float x) {
    return 1.f - 2.f * frcp(1.f + fexp2(2.885390081777927f * x));
}

// ---- LLC-coherent (sc1) relaxed atomics ----
__device__ __forceinline__ u32 ld_sc1_u32(const u32* p) {
    return __hip_atomic_load(p, __ATOMIC_RELAXED, __HIP_MEMORY_SCOPE_AGENT);
}
__device__ __forceinline__ void st_sc1_u32(u32* p, u32 v) {
    __hip_atomic_store(p, v, __ATOMIC_RELAXED, __HIP_MEMORY_SCOPE_AGENT);
}
__device__ __forceinline__ u64 ld_sc1_u64(const u64* p) {
    return __hip_atomic_load(p, __ATOMIC_RELAXED, __HIP_MEMORY_SCOPE_AGENT);
}
__device__ __forceinline__ short8 ldA(const u64* base) {
    union { u64 q[2]; short8 s; } u;
    u.q[0] = ld_sc1_u64(base);
    u.q[1] = ld_sc1_u64(base + 1);
    return u.s;
}

// ---- partial-order dataflow sync ----
// Each WG owns flags[w*16] (64B-spaced), bumped monotonically after each phase.
// bump(): per-wave vmcnt(0) drain + __syncthreads, THEN tid0 publishes — so a
// consumer observing flag>=gen is guaranteed the producer's sc1 data is at LLC.
__device__ __forceinline__ void poll_ge(const u32* f, int idx, u32 gen) {
    const u32* p = f + (u32)idx * 16;
    while (ld_sc1_u32(p) < gen) {}
}
__device__ __forceinline__ void bump(u32* f, u32 gen) {
    asm volatile("s_waitcnt vmcnt(0)" ::: "memory");
    __syncthreads();
    if (threadIdx.x == 0) st_sc1_u32(f + (u32)blockIdx.x * 16, gen);
}

// ---------------- prep kernels ----------------

// f32 [K,N] -> bf16 [N,K]
__global__ __launch_bounds__(256) void transpose_cvt(
    const float* __restrict__ src, u16* __restrict__ dst, int K, int N)
{
    __shared__ float tile[32][33];
    const int n0 = blockIdx.x * 32, k0 = blockIdx.y * 32;
    const int tx = threadIdx.x & 31, ty = threadIdx.x >> 5;
    #pragma unroll
    for (int j = 0; j < 32; j += 8)
        tile[ty + j][tx] = src[(size_t)(k0 + ty + j) * N + n0 + tx];
    __syncthreads();
    #pragma unroll
    for (int j = 0; j < 32; j += 8)
        dst[(size_t)(n0 + ty + j) * K + k0 + tx] = f2bf(tile[tx][ty + j]);
}

__global__ __launch_bounds__(256) void cvt_f32_bf16(
    const float* __restrict__ src, u16* __restrict__ dst)
{
    const size_t i = ((size_t)blockIdx.x * 256 + threadIdx.x) * 8;
    float4 v0 = *(const float4*)(src + i);
    float4 v1 = *(const float4*)(src + i + 4);
    uint4 pk;
    pk.x = (u32)f2bf(v0.x) | ((u32)f2bf(v0.y) << 16);
    pk.y = (u32)f2bf(v0.z) | ((u32)f2bf(v0.w) << 16);
    pk.z = (u32)f2bf(v1.x) | ((u32)f2bf(v1.y) << 16);
    pk.w = (u32)f2bf(v1.z) | ((u32)f2bf(v1.w) << 16);
    *(uint4*)(dst + i) = pk;
}

__global__ __launch_bounds__(128) void gather_emb_bf16(
    const int* __restrict__ idx, const float* __restrict__ emb, u16* __restrict__ out)
{
    const int r = blockIdx.x;
    const int token = idx[r];
    const int i = threadIdx.x * 4;
    float4 v = *(const float4*)(emb + (size_t)token * 512 + i);
    uint2 pk;
    pk.x = (u32)f2bf(v.x) | ((u32)f2bf(v.y) << 16);
    pk.y = (u32)f2bf(v.z) | ((u32)f2bf(v.w) << 16);
    *(uint2*)(out + (size_t)r * 512 + i) = pk;
}

// zero h (both parities, 16384 u32) + flag blocks (3072 u32)
__global__ __launch_bounds__(512) void init_state(u32* hg, u32* bar)
{
    const int i = blockIdx.x * 512 + threadIdx.x;
    hg[i] = 0u;
    if (blockIdx.x < 6) bar[blockIdx.x * 512 + threadIdx.x] = 0u;
}

// ---------------- MFMA GEMM:  C[M,N](f32) = A[M,K](bf16) * BT[N,K](bf16) + bias ----------------
__global__ __launch_bounds__(256) void gemm_bf16(
    const u16* __restrict__ A, const u16* __restrict__ BT,
    const float* __restrict__ bias, float* __restrict__ C,
    int M, int N, int K)
{
    __shared__ __align__(16) u16 As[128][40];
    __shared__ __align__(16) u16 Bs[128][40];
    const int tid  = threadIdx.x;
    const int lane = tid & 63, wave = tid >> 6;
    const int wm = (wave & 1) * 64, wn = (wave >> 1) * 64;
    const int lrow = lane & 15, lk = (lane >> 4) * 8;
    const int srow = tid >> 2, skof = (tid & 3) * 8;
    const size_t K_ = (size_t)K;
    const u16* Ag = A + ((size_t)blockIdx.y * 128 + srow) * K_ + skof;
    const u16* Bg = BT + ((size_t)blockIdx.x * 128 + srow) * K_ + skof;
    f32x4 acc[4][4] = {};
    for (int k0 = 0; k0 < K; k0 += 32) {
        uint4 a0 = *(const uint4*)(Ag + k0);
        uint4 a1 = *(const uint4*)(Ag + 64 * K_ + k0);
        uint4 b0 = *(const uint4*)(Bg + k0);
        uint4 b1 = *(const uint4*)(Bg + 64 * K_ + k0);
        __syncthreads();
        *(uint4*)&As[srow][skof]      = a0;
        *(uint4*)&As[srow + 64][skof] = a1;
        *(uint4*)&Bs[srow][skof]      = b0;
        *(uint4*)&Bs[srow + 64][skof] = b1;
        __syncthreads();
        short8 af[4], bf[4];
        #pragma unroll
        for (int i = 0; i < 4; ++i) af[i] = *(const short8*)&As[wm + i * 16 + lrow][lk];
        #pragma unroll
        for (int j = 0; j < 4; ++j) bf[j] = *(const short8*)&Bs[wn + j * 16 + lrow][lk];
        #pragma unroll
        for (int i = 0; i < 4; ++i)
            #pragma unroll
            for (int j = 0; j < 4; ++j)
                acc[i][j] = __builtin_amdgcn_mfma_f32_16x16x32_bf16(af[i], bf[j], acc[i][j], 0, 0, 0);
    }
    const int crow0 = blockIdx.y * 128 + wm + (lane >> 4) * 4;
    const int ccol0 = blockIdx.x * 128 + wn + (lane & 15);
    #pragma unroll
    for (int j = 0; j < 4; ++j) {
        const float bv = bias ? bias[ccol0 + j * 16] : 0.f;
        #pragma unroll
        for (int i = 0; i < 4; ++i)
            #pragma unroll
            for (int rr = 0; rr < 4; ++rr)
                C[(size_t)(crow0 + i * 16 + rr) * N + (ccol0 + j * 16)] = acc[i][j][rr] + bv;
    }
}

// ============ persistent encoder: 64 WGs, dataflow flags, h parity-buffered ============
__global__ __launch_bounds__(512) void enc_coop(
    const float* __restrict__ gx, const u16* __restrict__ Urz, const u16* __restrict__ Un,
    const float* __restrict__ brz, const float* __restrict__ bn,
    u32* __restrict__ hg, u32* __restrict__ rhg, u32* __restrict__ zg,
    u16* __restrict__ enc_hs, u16* __restrict__ spack,
    u32* __restrict__ flags)
{
    const int w = blockIdx.x, tid = threadIdx.x;
    const int v = tid >> 6, lane = tid & 63;
    const int nl = lane & 15, kq = lane >> 4;
    const u64* rq = (const u64*)rhg;
    for (int t = 0; t < SEQ; ++t) {
        const u32* hgA = hg + (t & 1) * 8192;
        u32*       hgW = hg + ((t + 1) & 1) * 8192;
        const u64* hq  = (const u64*)hgA;
        // ---- E1 wait: h ready = E2(t-1) WGs 0..31 ----
        { if (tid < 32) poll_ge(flags, tid, (u32)(2 * t)); __syncthreads(); }
        if (v < 2) {
            const int bt = v;
            const int n = w * 16 + nl;
            const int brow = bt * 16 + nl;
            float gxr_pf[4]; u32 hv_pf[4];
            #pragma unroll
            for (int rr = 0; rr < 4; ++rr) {
                const int b = bt * 16 + kq * 4 + rr;
                gxr_pf[rr] = gx[((size_t)(b * SEQ + t)) * 1536 + n];
                if (n < 512) hv_pf[rr] = ld_sc1_u32(hgA + b * 256 + (n >> 1));
            }
            const u16* wp = Urz + (size_t)n * 512 + kq * 8;
            f32x4 acc = {0.f, 0.f, 0.f, 0.f};
            #pragma unroll
            for (int k0 = 0; k0 < 512; k0 += 32) {
                short8 af = ldA(hq + brow * 128 + (k0 >> 2) + kq * 2);
                short8 bf = *(const short8*)(wp + k0);
                acc = __builtin_amdgcn_mfma_f32_16x16x32_bf16(af, bf, acc, 0, 0, 0);
            }
            if (n < 512) {               // r gate -> rh
                u32 pk[4];
                #pragma unroll
                for (int rr = 0; rr < 4; ++rr) {
                    const float r = sigmoid_f(gxr_pf[rr] + acc[rr] + brz[n]);
                    const float hold = bf2f((u16)((n & 1) ? (hv_pf[rr] >> 16) : (hv_pf[rr] & 0xFFFF)));
                    pk[rr] = (u32)f2bf(r * hold);
                }
                #pragma unroll
                for (int rr = 0; rr < 4; ++rr) {
                    u32 oth = (u32)__shfl_xor((int)pk[rr], 1);
                    if ((n & 1) == 0) {
                        const int b = bt * 16 + kq * 4 + rr;
                        st_sc1_u32(rhg + b * 256 + (n >> 1), (pk[rr] & 0xFFFF) | (oth << 16));
                    }
                }
            } else {                     // z gate
                #pragma unroll
                for (int rr = 0; rr < 4; ++rr) {
                    const int b = bt * 16 + kq * 4 + rr;
                    const float z = sigmoid_f(gxr_pf[rr] + acc[rr] + brz[n]);
                    st_sc1_u32(zg + (n - 512) * 32 + b, __float_as_uint(z));
                }
            }
        }
        bump(flags, (u32)(2 * t + 1));
        // ---- E2: only WGs 0..31; wait = ALL E1(t) (covers rh, zg, and h-read anti-dep) ----
        if (w < 32) {
            { if (tid < 64) poll_ge(flags, tid, (u32)(2 * t + 1)); __syncthreads(); }
            if (v < 2) {
                const int bt = v;
                const int n = w * 16 + nl;
                const int brow = bt * 16 + nl;
                float gxr_pf[4]; u32 hv_pf[4], zv_pf[4];
                #pragma unroll
                for (int rr = 0; rr < 4; ++rr) {
                    const int b = bt * 16 + kq * 4 + rr;
                    gxr_pf[rr] = gx[((size_t)(b * SEQ + t)) * 1536 + 1024 + n];
                    hv_pf[rr] = ld_sc1_u32(hgA + b * 256 + (n >> 1));
                    zv_pf[rr] = ld_sc1_u32(zg + n * 32 + b);
                }
                const u16* wp = Un + (size_t)n * 512 + kq * 8;
                f32x4 acc = {0.f, 0.f, 0.f, 0.f};
                #pragma unroll
                for (int k0 = 0; k0 < 512; k0 += 32) {
                    short8 af = ldA(rq + brow * 128 + (k0 >> 2) + kq * 2);
                    short8 bf = *(const short8*)(wp + k0);
                    acc = __builtin_amdgcn_mfma_f32_16x16x32_bf16(af, bf, acc, 0, 0, 0);
                }
                u32 pk[4];
                #pragma unroll
                for (int rr = 0; rr < 4; ++rr) {
                    const int b = bt * 16 + kq * 4 + rr;
                    const float nn = tanh_f(gxr_pf[rr] + acc[rr] + bn[n]);
                    const float z = __uint_as_float(zv_pf[rr]);
                    const float hold = bf2f((u16)((n & 1) ? (hv_pf[rr] >> 16) : (hv_pf[rr] & 0xFFFF)));
                    const float hn = (1.f - z) * hold + z * nn;
                    const u16 hb = f2bf(hn);
                    pk[rr] = (u32)hb;
                    enc_hs[((size_t)(b * SEQ + t)) * 512 + n] = hb;
                    spack[(((size_t)b * 16 + (t >> 3)) * 512 + n) * 8 + (t & 7)] = hb;
                }
                #pragma unroll
                for (int rr = 0; rr < 4; ++rr) {
                    u32 oth = (u32)__shfl_xor((int)pk[rr], 1);
                    if ((n & 1) == 0) {
                        const int b = bt * 16 + kq * 4 + rr;
                        st_sc1_u32(hgW + b * 256 + (n >> 1), (pk[rr] & 0xFFFF) | (oth << 16));
                    }
                }
            }
        }
        bump(flags, (u32)(2 * t + 2));
    }
}

// ============ persistent decoder: 96 WGs, dataflow flags, h parity-buffered ============
__global__ __launch_bounds__(512) void dec_coop(
    const float* __restrict__ gxe, const u16* __restrict__ wh_bf, const u16* __restrict__ spack,
    const float* __restrict__ attn_v, const float* __restrict__ brz, const float* __restrict__ bn,
    const u16* __restrict__ Urz, const u16* __restrict__ Ws,
    const u16* __restrict__ WxC, const u16* __restrict__ Un,
    u32* __restrict__ hg, u32* __restrict__ rhg, u32* __restrict__ ctxg,
    u32* __restrict__ zg, u32* __restrict__ gg, u32* __restrict__ aWsg,
    u16* __restrict__ hctx, u32* __restrict__ flags)
{
    const int w = blockIdx.x, tid = threadIdx.x;
    const int v = tid >> 6, lane = tid & 63;
    const int nl = lane & 15, kq = lane >> 4;
    __shared__ float hWsL[4 * 132], redE[512], attnL[128];
    __shared__ u16 ctxL[512];
    const u64* rq = (const u64*)rhg;
    const u64* cq = (const u64*)ctxg;
    for (int t = 0; t < SEQ; ++t) {
        const u32* hgA = hg + (t & 1) * 8192;
        u32*       hgW = hg + ((t + 1) & 1) * 8192;
        const u64* hq  = (const u64*)hgA;
        f32x4 aPk = {0.f, 0.f, 0.f, 0.f};
        // ---- P1 wait: h ready = P4(t-1) WGs 0..31 ----
        { if (tid < 32) poll_ge(flags, tid, (u32)(4 * t)); __syncthreads(); }
        if (v < 2) {
            const int bt = v;
            const int n = w * 16 + nl;
            const int brow = bt * 16 + nl;
            const u16* wp = (n < 1024 ? Urz + (size_t)n * 512
                                      : Ws + (size_t)(n - 1024) * 512) + kq * 8;
            f32x4 acc = {0.f, 0.f, 0.f, 0.f};
            #pragma unroll
            for (int k0 = 0; k0 < 512; k0 += 32) {
                short8 af = ldA(hq + brow * 128 + (k0 >> 2) + kq * 2);
                short8 bf = *(const short8*)(wp + k0);
                acc = __builtin_amdgcn_mfma_f32_16x16x32_bf16(af, bf, acc, 0, 0, 0);
            }
            if (n < 1024) {
                aPk = acc;               // persists in regs to P3
            } else {
                #pragma unroll
                for (int rr = 0; rr < 4; ++rr) {
                    const int b = bt * 16 + kq * 4 + rr;
                    st_sc1_u32(aWsg + (n - 1024) * 32 + b, __float_as_uint(acc[rr]));
                }
            }
        }
        bump(flags, (u32)(4 * t + 1));
        // ---- P2: attention, WGs 0..31 (b = w) ----
        if (w < 32) {
            {   // wait: aWs = P1(t)[64..95]; ctx anti-dep = ALL P3(t-1)
                const int l = tid;
                if (l < 96) {
                    int g0 = 4 * t - 1; if (g0 < 0) g0 = 0;
                    u32 g = (l >= 64) ? (u32)(4 * t + 1) : (u32)g0;
                    poll_ge(flags, l, g);
                }
                __syncthreads();
            }
            const int b = w;
            hWsL[(tid >> 7) * 132 + (tid & 127)] = __uint_as_float(ld_sc1_u32(aWsg + tid * 32 + b));
            __syncthreads();
            {
                const int s = tid >> 2, q = tid & 3;
                const u16* whr = wh_bf + ((size_t)(b * SEQ + s)) * 512 + q * 128;
                const float* avq = attn_v + q * 128;
                const float* hwq = &hWsL[q * 132];
                float e = 0.f;
                #pragma unroll 4
                for (int i = 0; i < 128; i += 8) {
                    uint4 wv = *(const uint4*)(whr + i);
                    float4 h0 = *(const float4*)(hwq + i);
                    float4 h1 = *(const float4*)(hwq + i + 4);
                    float4 v0 = *(const float4*)(avq + i);
                    float4 v1 = *(const float4*)(avq + i + 4);
                    e += v0.x * tanh_f(bf2f((u16)(wv.x & 0xFFFF)) + h0.x)
                       + v0.y * tanh_f(bf2f((u16)(wv.x >> 16))    + h0.y)
                       + v0.z * tanh_f(bf2f((u16)(wv.y & 0xFFFF)) + h0.z)
                       + v0.w * tanh_f(bf2f((u16)(wv.y >> 16))    + h0.w)
                       + v1.x * tanh_f(bf2f((u16)(wv.z & 0xFFFF)) + h1.x)
                       + v1.y * tanh_f(bf2f((u16)(wv.z >> 16))    + h1.y)
                       + v1.z * tanh_f(bf2f((u16)(wv.w & 0xFFFF)) + h1.z)
                       + v1.w * tanh_f(bf2f((u16)(wv.w >> 16))    + h1.w);
                }
                redE[tid] = e;
            }
            __syncthreads();
            if (tid < 64) {
                float e0 = redE[4 * tid] + redE[4 * tid + 1] + redE[4 * tid + 2] + redE[4 * tid + 3];
                float e1 = redE[4 * (tid + 64)] + redE[4 * (tid + 64) + 1]
                         + redE[4 * (tid + 64) + 2] + redE[4 * (tid + 64) + 3];
                float m = fmaxf(e0, e1);
                for (int o = 32; o >= 1; o >>= 1) m = fmaxf(m, __shfl_xor(m, o));
                float p0 = fexp2((e0 - m) * 1.442695040888963f);
                float p1 = fexp2((e1 - m) * 1.442695040888963f);
                float ss = p0 + p1;
                for (int o = 32; o >= 1; o >>= 1) ss += __shfl_xor(ss, o);
                const float inv = frcp(ss);
                attnL[tid]      = p0 * inv;
                attnL[tid + 64] = p1 * inv;
            }
            __syncthreads();
            {
                const int d = tid;
                float cv = 0.f;
                const u16* sp = spack + ((size_t)b * 16 * 512 + d) * 8;
                #pragma unroll 4
                for (int sb = 0; sb < 16; ++sb) {
                    uint4 sv = *(const uint4*)(sp + (size_t)sb * 4096);
                    const float* al = &attnL[sb * 8];
                    cv += al[0] * bf2f((u16)(sv.x & 0xFFFF)) + al[1] * bf2f((u16)(sv.x >> 16))
                        + al[2] * bf2f((u16)(sv.y & 0xFFFF)) + al[3] * bf2f((u16)(sv.y >> 16))
                        + al[4] * bf2f((u16)(sv.z & 0xFFFF)) + al[5] * bf2f((u16)(sv.z >> 16))
                        + al[6] * bf2f((u16)(sv.w & 0xFFFF)) + al[7] * bf2f((u16)(sv.w >> 16));
                }
                const u16 cb = f2bf(cv);
                ctxL[d] = cb;
                hctx[((size_t)(b * SEQ + t)) * 1024 + 512 + d] = cb;
            }
            __syncthreads();
            if (tid < 256) {
                u32 pk = (u32)ctxL[2 * tid] | ((u32)ctxL[2 * tid + 1] << 16);
                st_sc1_u32(ctxg + b * 256 + tid, pk);
            }
        }
        bump(flags, (u32)(4 * t + 2));
        // ---- P3 wait: ctx = P2(t) WGs 0..31 ----
        { if (tid < 32) poll_ge(flags, tid, (u32)(4 * t + 2)); __syncthreads(); }
        if (v < 2) {
            const int bt = v;
            const int n = w * 16 + nl;
            const int brow = bt * 16 + nl;
            float gxr_pf[4]; u32 hv_pf[4];
            #pragma unroll
            for (int rr = 0; rr < 4; ++rr) {
                const int b = bt * 16 + kq * 4 + rr;
                gxr_pf[rr] = gxe[((size_t)(b * SEQ + t)) * 1536 + n];
                if (n < 512) hv_pf[rr] = ld_sc1_u32(hgA + b * 256 + (n >> 1));
            }
            const u16* wp = WxC + (size_t)n * 512 + kq * 8;
            f32x4 acc = {0.f, 0.f, 0.f, 0.f};
            #pragma unroll
            for (int k0 = 0; k0 < 512; k0 += 32) {
                short8 af = ldA(cq + brow * 128 + (k0 >> 2) + kq * 2);
                short8 bf = *(const short8*)(wp + k0);
                acc = __builtin_amdgcn_mfma_f32_16x16x32_bf16(af, bf, acc, 0, 0, 0);
            }
            if (n < 512) {               // r gate -> rh
                u32 pk[4];
                #pragma unroll
                for (int rr = 0; rr < 4; ++rr) {
                    const float r = sigmoid_f(gxr_pf[rr] + acc[rr] + aPk[rr] + brz[n]);
                    const float hold = bf2f((u16)((n & 1) ? (hv_pf[rr] >> 16) : (hv_pf[rr] & 0xFFFF)));
                    pk[rr] = (u32)f2bf(r * hold);
                }
                #pragma unroll
                for (int rr = 0; rr < 4; ++rr) {
                    u32 oth = (u32)__shfl_xor((int)pk[rr], 1);
                    if ((n & 1) == 0) {
                        const int b = bt * 16 + kq * 4 + rr;
                        st_sc1_u32(rhg + b * 256 + (n >> 1), (pk[rr] & 0xFFFF) | (oth << 16));
                    }
                }
            } else if (n < 1024) {       // z gate
                #pragma unroll
                for (int rr = 0; rr < 4; ++rr) {
                    const int b = bt * 16 + kq * 4 + rr;
                    const float z = sigmoid_f(gxr_pf[rr] + acc[rr] + aPk[rr] + brz[n]);
                    st_sc1_u32(zg + (n - 512) * 32 + b, __float_as_uint(z));
                }
            } else {                     // n-gate pre-activation
                #pragma unroll
                for (int rr = 0; rr < 4; ++rr) {
                    const int b = bt * 16 + kq * 4 + rr;
                    st_sc1_u32(gg + (n - 1024) * 32 + b, __float_as_uint(gxr_pf[rr] + acc[rr]));
                }
            }
        }
        bump(flags, (u32)(4 * t + 3));
        // ---- P4: WGs 0..31; wait: rh = P3(t)[0..31]; zg slice = P3 WG 32+w; gg slice = P3 WG 64+w ----
        if (w < 32) {
            {
                const int l = tid;
                if (l < 32) poll_ge(flags, l, (u32)(4 * t + 3));
                else if (l == 32) poll_ge(flags, 32 + w, (u32)(4 * t + 3));
                else if (l == 33) poll_ge(flags, 64 + w, (u32)(4 * t + 3));
                __syncthreads();
            }
            if (v < 2) {
                const int bt = v;
                const int n = w * 16 + nl;
                const int brow = bt * 16 + nl;
                u32 gv_pf[4], zv_pf[4], hv_pf[4];
                #pragma unroll
                for (int rr = 0; rr < 4; ++rr) {
                    const int b = bt * 16 + kq * 4 + rr;
                    gv_pf[rr] = ld_sc1_u32(gg + n * 32 + b);
                    zv_pf[rr] = ld_sc1_u32(zg + n * 32 + b);
                    hv_pf[rr] = ld_sc1_u32(hgA + b * 256 + (n >> 1));
                }
                const u16* wp = Un + (size_t)n * 512 + kq * 8;
                f32x4 acc = {0.f, 0.f, 0.f, 0.f};
                #pragma unroll
                for (int k0 = 0; k0 < 512; k0 += 32) {
                    short8 af = ldA(rq + brow * 128 + (k0 >> 2) + kq * 2);
                    short8 bf = *(const short8*)(wp + k0);
                    acc = __builtin_amdgcn_mfma_f32_16x16x32_bf16(af, bf, acc, 0, 0, 0);
                }
                u32 pk[4];
                #pragma unroll
                for (int rr = 0; rr < 4; ++rr) {
                    const int b = bt * 16 + kq * 4 + rr;
                    const float nn = tanh_f(__uint_as_float(gv_pf[rr]) + acc[rr] + bn[n]);
                    const float z = __uint_as_float(zv_pf[rr]);
                    const float hold = bf2f((u16)((n & 1) ? (hv_pf[rr] >> 16) : (hv_pf[rr] & 0xFFFF)));
                    const float hn = (1.f - z) * hold + z * nn;
                    const u16 hb = f2bf(hn);
                    pk[rr] = (u32)hb;
                    hctx[((size_t)(b * SEQ + t)) * 1024 + n] = hb;
                }
                #pragma unroll
                for (int rr = 0; rr < 4; ++rr) {
                    u32 oth = (u32)__shfl_xor((int)pk[rr], 1);
                    if ((n & 1) == 0) {
                        const int b = bt * 16 + kq * 4 + rr;
                        st_sc1_u32(hgW + b * 256 + (n >> 1), (pk[rr] & 0xFFFF) | (oth << 16));
                    }
                }
            }
        }
        bump(flags, (u32)(4 * t + 4));
    }
}

// ---------------- log_softmax: 2-pass (online max+sum), in-place on [4096, 32000] ----------------
__global__ __launch_bounds__(256) void log_softmax_rows(float* __restrict__ out)
{
    const int row = blockIdx.x, tid = threadIdx.x;
    float* p = out + (size_t)row * VTOK;
    __shared__ float rbM[4], rbS[4];
    const float L2E = 1.442695040888963f;
    float m = -3.0e38f, s = 0.f;
    for (int i = tid * 4; i < VTOK; i += 1024) {
        float4 v = *(const float4*)(p + i);
        float lm = fmaxf(fmaxf(v.x, v.y), fmaxf(v.z, v.w));
        float nm = fmaxf(m, lm);
        s = s * fexp2((m - nm) * L2E)
          + fexp2((v.x - nm) * L2E) + fexp2((v.y - nm) * L2E)
          + fexp2((v.z - nm) * L2E) + fexp2((v.w - nm) * L2E);
        m = nm;
    }
    for (int o = 32; o >= 1; o >>= 1) {
        float om = __shfl_xor(m, o), os = __shfl_xor(s, o);
        float nm = fmaxf(m, om);
        s = s * fexp2((m - nm) * L2E) + os * fexp2((om - nm) * L2E);
        m = nm;
    }
    if ((tid & 63) == 0) { rbM[tid >> 6] = m; rbS[tid >> 6] = s; }
    __syncthreads();
    {
        float fm = fmaxf(fmaxf(rbM[0], rbM[1]), fmaxf(rbM[2], rbM[3]));
        float fs = rbS[0] * fexp2((rbM[0] - fm) * L2E) + rbS[1] * fexp2((rbM[1] - fm) * L2E)
                 + rbS[2] * fexp2((rbM[2] - fm) * L2E) + rbS[3] * fexp2((rbM[3] - fm) * L2E);
        m = fm; s = fs;
    }
    const float lse = m + __builtin_amdgcn_logf(s) * 0.6931471805599453f;
    for (int i = tid * 4; i < VTOK; i += 1024) {
        float4 v = *(const float4*)(p + i);
        v.x -= lse; v.y -= lse; v.z -= lse; v.w -= lse;
        *(float4*)(p + i) = v;
    }
}

// ---------------- host launcher ----------------
extern "C" void kernel_launch(void* const* d_in, const int* in_sizes, int n_in,
                              void* d_out, int out_size, void* d_ws, size_t ws_size,
                              hipStream_t stream)
{
    (void)in_sizes; (void)n_in; (void)out_size; (void)ws_size;
    const int*   src       = (const int*)  d_in[0];
    const int*   tgt       = (const int*)  d_in[1];
    const float* enc_embed = (const float*)d_in[2];
    const float* enc_Wx    = (const float*)d_in[3];
    const float* enc_bx    = (const float*)d_in[4];
    const float* enc_Urz   = (const float*)d_in[5];
    const float* enc_brz   = (const float*)d_in[6];
    const float* enc_Un    = (const float*)d_in[7];
    const float* enc_bn    = (const float*)d_in[8];
    const float* dec_embed = (const float*)d_in[9];
    const float* dec_Wx    = (const float*)d_in[10];
    const float* dec_bx    = (const float*)d_in[11];
    const float* dec_Urz   = (const float*)d_in[12];
    const float* dec_brz   = (const float*)d_in[13];
    const float* dec_Un    = (const float*)d_in[14];
    const float* dec_bn    = (const float*)d_in[15];
    const float* attn_Wh   = (const float*)d_in[16];
    const float* attn_Ws   = (const float*)d_in[17];
    const float* attn_v    = (const float*)d_in[18];
    const float* out_W     = (const float*)d_in[19];
    const float* out_b     = (const float*)d_in[20];

    // --- scratch in d_out (524,288,000 B); all dead before the final GEMM overwrites ---
    char* ob = (char*)d_out;
    float* gx_enc   = (float*)(ob + 0);              // 25165824
    float* gxe_dec  = (float*)(ob + 25165824);       // 25165824
    float* wh_enc   = (float*)(ob + 50331648);       // 8388608
    u16*   Aenc     = (u16*)(ob + 58720256);         // 4194304
    u16*   Adec     = (u16*)(ob + 62914560);         // 4194304
    u16*   enc_hs   = (u16*)(ob + 67108864);         // 4194304
    u16*   spack    = (u16*)(ob + 71303168);         // 4194304
    u16*   wh_bf    = (u16*)(ob + 75497472);         // 4194304
    u16*   encWxT   = (u16*)(ob + 79691776);         // 1572864
    u16*   decWxET  = (u16*)(ob + 81264640);         // 1572864
    u16*   WhT      = (u16*)(ob + 82837504);         // 524288
    u16*   UrzET    = (u16*)(ob + 83361792);         // 1048576
    u16*   UnET     = (u16*)(ob + 84410368);         // 524288
    u16*   UrzDT    = (u16*)(ob + 84934656);         // 1048576
    u16*   UnDT     = (u16*)(ob + 85983232);         // 524288
    u16*   WsT      = (u16*)(ob + 86507520);         // 524288
    u16*   WxCT     = (u16*)(ob + 87031808);         // 1572864
    u32*   hg       = (u32*)(ob + 88604672);         // 65536 (2 parities x 32KB)
    u32*   rhg      = (u32*)(ob + 88670208);         // 32768
    u32*   ctxg     = (u32*)(ob + 88702976);         // 32768
    u32*   zg       = (u32*)(ob + 88735744);         // 65536
    u32*   gg       = (u32*)(ob + 88801280);         // 65536
    u32*   aWsg     = (u32*)(ob + 88866816);         // 65536
    u32*   barp     = (u32*)(ob + 88932352);         // 12288: encFlags (96x16 u32), decFlags @ +6144B

    // --- d_ws: only what must coexist with the final GEMM's output ---
    char* wb = (char*)d_ws;
    u16* outWT = (u16*)(wb + 0);          // 65536000
    u16* hctx  = (u16*)(wb + 65536000);   // 8388608

    // prep: all weights -> bf16 [N][K]
    transpose_cvt<<<dim3(48, 16),   256, 0, stream>>>(enc_Wx,  encWxT, 512, 1536);
    transpose_cvt<<<dim3(48, 16),   256, 0, stream>>>(dec_Wx,  decWxET,512, 1536);
    transpose_cvt<<<dim3(16, 16),   256, 0, stream>>>(attn_Wh, WhT,    512, 512);
    transpose_cvt<<<dim3(1000, 32), 256, 0, stream>>>(out_W,   outWT, 1024, 32000);
    transpose_cvt<<<dim3(32, 16),   256, 0, stream>>>(enc_Urz, UrzET,  512, 1024);
    transpose_cvt<<<dim3(16, 16),   256, 0, stream>>>(enc_Un,  UnET,   512, 512);
    transpose_cvt<<<dim3(32, 16),   256, 0, stream>>>(dec_Urz, UrzDT,  512, 1024);
    transpose_cvt<<<dim3(16, 16),   256, 0, stream>>>(dec_Un,  UnDT,   512, 512);
    transpose_cvt<<<dim3(16, 16),   256, 0, stream>>>(attn_Ws, WsT,    512, 512);
    transpose_cvt<<<dim3(48, 16),   256, 0, stream>>>(dec_Wx + (size_t)512 * 1536, WxCT, 512, 1536);
    gather_emb_bf16<<<4096, 128, 0, stream>>>(src, enc_embed, Aenc);
    gather_emb_bf16<<<4096, 128, 0, stream>>>(tgt, dec_embed, Adec);

    // batched input-projection GEMMs
    gemm_bf16<<<dim3(12, 32), 256, 0, stream>>>(Aenc, encWxT,  enc_bx, gx_enc,  4096, 1536, 512);
    gemm_bf16<<<dim3(12, 32), 256, 0, stream>>>(Adec, decWxET, dec_bx, gxe_dec, 4096, 1536, 512);

    init_state<<<32, 512, 0, stream>>>(hg, barp);

    // encoder (persistent, dataflow flags, 64 WGs)
    {
        u32* encF = barp;
        void* args[] = { (void*)&gx_enc, (void*)&UrzET, (void*)&UnET, (void*)&enc_brz,
                         (void*)&enc_bn, (void*)&hg, (void*)&rhg, (void*)&zg,
                         (void*)&enc_hs, (void*)&spack, (void*)&encF };
        hipLaunchCooperativeKernel((void*)enc_coop, dim3(64), dim3(512), args, 0, stream);
    }

    // wh_enc = enc_hs @ attn_Wh; -> bf16
    gemm_bf16<<<dim3(4, 32), 256, 0, stream>>>(enc_hs, WhT, nullptr, wh_enc, 4096, 512, 512);
    cvt_f32_bf16<<<1024, 256, 0, stream>>>(wh_enc, wh_bf);

    // decoder (persistent, dataflow flags, 96 WGs; h carried in hg parity 0 — enc ends at t=128 even)
    {
        u32* decF = barp + 1536;
        void* args[] = { (void*)&gxe_dec, (void*)&wh_bf, (void*)&spack, (void*)&attn_v,
                         (void*)&dec_brz, (void*)&dec_bn, (void*)&UrzDT, (void*)&WsT,
                         (void*)&WxCT, (void*)&UnDT, (void*)&hg, (void*)&rhg, (void*)&ctxg,
                         (void*)&zg, (void*)&gg, (void*)&aWsg, (void*)&hctx, (void*)&decF };
        hipLaunchCooperativeKernel((void*)dec_coop, dim3(96), dim3(512), args, 0, stream);
    }

    // output projection (overwrites ALL of d_out) + in-place log_softmax
    gemm_bf16<<<dim3(250, 32), 256, 0, stream>>>(hctx, outWT, out_b, (float*)d_out, 4096, VTOK, 1024);
    log_softmax_rows<<<4096, 256, 0, stream>>>((float*)d_out);
}